// Round 1
// baseline (1411.498 us; speedup 1.0000x reference)
//
#include <hip/hip_runtime.h>
#include <math.h>

#define B_ 4
#define C_ 128
#define H_ 64
#define W_ 64

// ---- workspace layout (float offsets) ----
// xt1: [4][4096][128], xt2: [4][1024][128], xt4: [4][256][128]
// att2: [4][128][1024], att4: [4][128][256]   (attention outputs, [B][C][N])
static const size_t XT1_OFF  = 0;
static const size_t XT2_OFF  = XT1_OFF + (size_t)B_ * 4096 * C_;   // 2,097,152
static const size_t XT4_OFF  = XT2_OFF + (size_t)B_ * 1024 * C_;   // +524,288
static const size_t ATT2_OFF = XT4_OFF + (size_t)B_ * 256  * C_;   // +131,072
static const size_t ATT4_OFF = ATT2_OFF + (size_t)B_ * 1024 * C_;  // +524,288
// total = 3,407,872 floats = 13.6 MB

// ---------------- pool + transpose:  x[B][C][H][W] -> xt[B][N][C], N=(H/S)*(W/S)
template<int S>
__global__ __launch_bounds__(256) void pool_tr_kernel(const float* __restrict__ x,
                                                      float* __restrict__ xt) {
    constexpr int HS = H_ / S, WS = W_ / S;
    constexpr int ROWSTRIDE = S * 64 + 1;           // +1 pad to break bank aliasing
    __shared__ float lds[32 * ROWSTRIDE];
    const int hp = blockIdx.x;                      // pooled row
    const int c0 = blockIdx.y * 32;                 // channel chunk
    const int b  = blockIdx.z;
    const int t  = threadIdx.x;

    constexpr int RN = 32 * S * 64;                 // staged region (floats)
    for (int e = t; e < RN; e += 256) {
        int ci  = e / (S * 64);
        int rem = e - ci * (S * 64);
        int i   = rem >> 6;
        int w   = rem & 63;
        lds[ci * ROWSTRIDE + rem] =
            x[((size_t)(b * C_ + c0 + ci) * H_ + (hp * S + i)) * W_ + w];
    }
    __syncthreads();

    constexpr int NV = 32 * WS;
    constexpr float inv = 1.0f / (S * S);
    for (int v = t; v < NV; v += 256) {
        int ci = v & 31;
        int wp = v >> 5;
        float s = 0.f;
        #pragma unroll
        for (int i = 0; i < S; ++i)
            #pragma unroll
            for (int j = 0; j < S; ++j)
                s += lds[ci * ROWSTRIDE + i * 64 + wp * S + j];
        xt[((size_t)b * (HS * WS) + hp * WS + wp) * C_ + c0 + ci] = s * inv;
    }
}

// ---------------- flash attention, fp32 baseline
// xt: [B][N][C]  ->  out: [B][C][N]  (out[b][c][n] = sum_m softmax_m(q_n.k_m) * xt[b][m][c])
template<int N>
__global__ __launch_bounds__(256) void attn_kernel(const float* __restrict__ xt,
                                                   float* __restrict__ out) {
    __shared__ float qT[32 * 132];
    __shared__ float kT[32 * 132];
    const int b  = blockIdx.y;
    const int n0 = blockIdx.x * 32;
    const int t  = threadIdx.x;
    const int r  = t >> 3;          // row 0..31
    const int tc = t & 7;           // lane-in-row 0..7
    const int lane = t & 63;
    const float* xb = xt + (size_t)b * N * C_;

    // load Q tile (32 x 128), coalesced float4
    #pragma unroll
    for (int it = 0; it < 4; ++it) {
        int e4  = it * 1024 + t * 4;
        int row = e4 >> 7;
        int col = e4 & 127;
        float4 v = *reinterpret_cast<const float4*>(xb + (size_t)(n0 + row) * C_ + col);
        *reinterpret_cast<float4*>(&qT[row * 132 + col]) = v;
    }

    float acc[16];
    #pragma unroll
    for (int i = 0; i < 16; ++i) acc[i] = 0.f;
    float m_run = -INFINITY, l_run = 0.f;

    for (int m0 = 0; m0 < N; m0 += 32) {
        __syncthreads();            // previous iter done reading kT
        #pragma unroll
        for (int it = 0; it < 4; ++it) {
            int e4  = it * 1024 + t * 4;
            int row = e4 >> 7;
            int col = e4 & 127;
            float4 v = *reinterpret_cast<const float4*>(xb + (size_t)(m0 + row) * C_ + col);
            *reinterpret_cast<float4*>(&kT[row * 132 + col]) = v;
        }
        __syncthreads();

        // scores: this thread owns m = tc*4 + j, j=0..3 for row r
        float s[4] = {0.f, 0.f, 0.f, 0.f};
        for (int c = 0; c < 128; c += 4) {
            float4 qv = *reinterpret_cast<const float4*>(&qT[r * 132 + c]);
            #pragma unroll
            for (int j = 0; j < 4; ++j) {
                float4 kv = *reinterpret_cast<const float4*>(&kT[(tc * 4 + j) * 132 + c]);
                s[j] += qv.x * kv.x + qv.y * kv.y + qv.z * kv.z + qv.w * kv.w;
            }
        }

        // online softmax (8 lanes per row; 8-aligned groups inside the wave)
        float tm = fmaxf(fmaxf(s[0], s[1]), fmaxf(s[2], s[3]));
        #pragma unroll
        for (int o = 1; o < 8; o <<= 1) tm = fmaxf(tm, __shfl_xor(tm, o, 64));
        float new_m = fmaxf(m_run, tm);
        float scale = __expf(m_run - new_m);       // exp(-inf)=0 on first tile
        float p[4], ts = 0.f;
        #pragma unroll
        for (int j = 0; j < 4; ++j) { p[j] = __expf(s[j] - new_m); ts += p[j]; }
        #pragma unroll
        for (int o = 1; o < 8; o <<= 1) ts += __shfl_xor(ts, o, 64);
        l_run = l_run * scale + ts;
        m_run = new_m;
        #pragma unroll
        for (int i = 0; i < 16; ++i) acc[i] *= scale;

        // PV: acc[c] += p[m] * kT[m][c], this thread covers c = tc*16 .. tc*16+15
        const int base = lane & ~7;
        #pragma unroll
        for (int owner = 0; owner < 8; ++owner) {
            #pragma unroll
            for (int j = 0; j < 4; ++j) {
                float pm = __shfl(p[j], base | owner, 64);
                const float* kr = &kT[(owner * 4 + j) * 132 + tc * 16];
                #pragma unroll
                for (int cc = 0; cc < 4; ++cc) {
                    float4 kv = *reinterpret_cast<const float4*>(kr + cc * 4);
                    acc[cc * 4 + 0] += pm * kv.x;
                    acc[cc * 4 + 1] += pm * kv.y;
                    acc[cc * 4 + 2] += pm * kv.z;
                    acc[cc * 4 + 3] += pm * kv.w;
                }
            }
        }
    }

    const float invl = 1.0f / l_run;
    const int n = n0 + r;
    #pragma unroll
    for (int i = 0; i < 16; ++i) {
        int c = tc * 16 + i;
        out[((size_t)b * C_ + c) * N + n] = acc[i] * invl;
    }
}

// ---------------- bilinear upsample (half-pixel centers, clamp) + sum
template<int HS>
__device__ inline float bilin(const float* __restrict__ a, int h, int w) {
    constexpr float sc = (float)HS / 64.0f;
    float sh = (h + 0.5f) * sc - 0.5f;
    float sw = (w + 0.5f) * sc - 0.5f;
    int h0 = (int)floorf(sh); float fh = sh - (float)h0;
    int w0 = (int)floorf(sw); float fw = sw - (float)w0;
    int h0c = max(h0, 0), h1c = min(h0 + 1, HS - 1);
    int w0c = max(w0, 0), w1c = min(w0 + 1, HS - 1);
    float v00 = a[h0c * HS + w0c], v01 = a[h0c * HS + w1c];
    float v10 = a[h1c * HS + w0c], v11 = a[h1c * HS + w1c];
    return (1.f - fh) * ((1.f - fw) * v00 + fw * v01)
         +        fh  * ((1.f - fw) * v10 + fw * v11);
}

__global__ __launch_bounds__(256) void combine_kernel(float* __restrict__ out,
                                                      const float* __restrict__ att2,
                                                      const float* __restrict__ att4) {
    int e = blockIdx.x * 256 + threadIdx.x;
    if (e >= B_ * C_ * H_ * W_) return;
    int w  = e & 63;
    int h  = (e >> 6) & 63;
    int bc = e >> 12;                // b*C + c
    float v = out[e];                // scale-1 attention already here
    v += bilin<32>(att2 + (size_t)bc * 1024, h, w);
    v += bilin<16>(att4 + (size_t)bc * 256,  h, w);
    out[e] = v;
}

extern "C" void kernel_launch(void* const* d_in, const int* in_sizes, int n_in,
                              void* d_out, int out_size, void* d_ws, size_t ws_size,
                              hipStream_t stream) {
    const float* x = (const float*)d_in[0];
    float* out = (float*)d_out;
    float* ws  = (float*)d_ws;
    float* xt1  = ws + XT1_OFF;
    float* xt2  = ws + XT2_OFF;
    float* xt4  = ws + XT4_OFF;
    float* att2 = ws + ATT2_OFF;
    float* att4 = ws + ATT4_OFF;

    pool_tr_kernel<1><<<dim3(64, 4, B_), 256, 0, stream>>>(x, xt1);
    pool_tr_kernel<2><<<dim3(32, 4, B_), 256, 0, stream>>>(x, xt2);
    pool_tr_kernel<4><<<dim3(16, 4, B_), 256, 0, stream>>>(x, xt4);

    attn_kernel<4096><<<dim3(4096 / 32, B_), 256, 0, stream>>>(xt1, out);
    attn_kernel<1024><<<dim3(1024 / 32, B_), 256, 0, stream>>>(xt2, att2);
    attn_kernel<256 ><<<dim3(256  / 32, B_), 256, 0, stream>>>(xt4, att4);

    combine_kernel<<<(B_ * C_ * H_ * W_ + 255) / 256, 256, 0, stream>>>(out, att2, att4);
}

// Round 2
// 207.253 us; speedup vs baseline: 6.8105x; 6.8105x over previous
//
#include <hip/hip_runtime.h>
#include <hip/hip_bf16.h>
#include <math.h>

typedef __attribute__((ext_vector_type(8))) short bf16x8;
typedef __attribute__((ext_vector_type(4))) float f32x4;

#define B_ 4
#define C_ 128

// ---- workspace byte offsets ----
#define XT1_B   0ull
#define XT2_B   4194304ull
#define XT4_B   5242880ull
#define XTT1_B  5505024ull
#define XTT2_B  9699328ull
#define XTT4_B  10747904ull
#define ATT2_B  11010048ull
#define ATT4_B  13107200ull
// total 13,631,488 bytes (same footprint class as round-1's 13.6 MB)

__device__ __forceinline__ unsigned short f2bf(float f) {
    unsigned int u = __builtin_bit_cast(unsigned int, f);
    return (unsigned short)((u + 0x7FFFu + ((u >> 16) & 1u)) >> 16);   // RNE, no NaN inputs here
}

__device__ __forceinline__ void gload_lds16(const void* g, void* l) {
    __builtin_amdgcn_global_load_lds(
        (const __attribute__((address_space(1))) unsigned int*)g,
        (__attribute__((address_space(3))) unsigned int*)l, 16, 0, 0);
}

// ---------------- pool + transpose: x[B][C][64][64] -> xt[B][N][C] bf16, xtT[B][C][N] bf16
template<int S>
__global__ __launch_bounds__(256) void pool_tr(const float* __restrict__ x,
                                               unsigned short* __restrict__ xt,
                                               unsigned short* __restrict__ xtT) {
    constexpr int WS = 64 / S;
    constexpr int N  = WS * WS;
    constexpr int RS = S * 64 + 1;
    __shared__ float lds[32 * RS];
    const int hp = blockIdx.x;           // pooled row
    const int c0 = blockIdx.y * 32;      // channel chunk
    const int b  = blockIdx.z;
    const int t  = threadIdx.x;

    for (int e = t; e < 32 * S * 64; e += 256) {
        int ci  = e / (S * 64);
        int rem = e - ci * (S * 64);
        lds[ci * RS + rem] =
            x[((size_t)(b * C_ + c0 + ci) * 64 + (hp * S + (rem >> 6))) * 64 + (rem & 63)];
    }
    __syncthreads();

    constexpr float inv = 1.0f / (S * S);
    // pass 1: xt[n][c]
    for (int v = t; v < 32 * WS; v += 256) {
        int ci = v & 31, wp = v >> 5;
        float s = 0.f;
        #pragma unroll
        for (int i = 0; i < S; ++i)
            #pragma unroll
            for (int j = 0; j < S; ++j) s += lds[ci * RS + i * 64 + wp * S + j];
        xt[((size_t)b * N + hp * WS + wp) * C_ + c0 + ci] = f2bf(s * inv);
    }
    // pass 2: xtT[c][n]  (coalesced along n)
    for (int v = t; v < 32 * WS; v += 256) {
        int wp = v & (WS - 1), ci = v / WS;
        float s = 0.f;
        #pragma unroll
        for (int i = 0; i < S; ++i)
            #pragma unroll
            for (int j = 0; j < S; ++j) s += lds[ci * RS + i * 64 + wp * S + j];
        xtT[((size_t)(b * C_ + c0 + ci)) * N + hp * WS + wp] = f2bf(s * inv);
    }
}

// ---------------- MFMA flash attention
// xt [B][N][C] bf16, xtT [B][C][N] bf16 -> out [B][C][N] f32
// S^T = mfma(K_frag, Q_frag): lane holds S[n=lane&15][m], softmax per-lane,
// P^T D-regs feed PV B-operand directly via permuted m-tiles.
template<int N>
__global__ __launch_bounds__(128) void attn_mfma(const unsigned short* __restrict__ xt,
                                                 const unsigned short* __restrict__ xtT,
                                                 float* __restrict__ out) {
    __shared__ char lds[32768];          // [0,16K): K tile [64][128] bf16; [16K,32K): V^T [128][64] bf16
    const int b   = blockIdx.y;
    const int n0  = blockIdx.x * 64;
    const int tid = threadIdx.x;
    const int w = tid >> 6, lane = tid & 63;
    const int g = lane >> 4, rho = lane & 15;

    const char* xb  = (const char*)(xt  + (size_t)b * N * C_);
    const char* xtb = (const char*)(xtT + (size_t)b * C_ * N);

    // Q fragments (B-operand of S^T mfma): q[n][32kc + 8g + i]
    bf16x8 qf[2][4];
    #pragma unroll
    for (int tt = 0; tt < 2; ++tt) {
        const char* qr = xb + (size_t)(n0 + w * 32 + tt * 16 + rho) * 256;
        #pragma unroll
        for (int kc = 0; kc < 4; ++kc)
            qf[tt][kc] = *(const bf16x8*)(qr + kc * 64 + g * 16);
    }

    f32x4 acc[2][8];
    #pragma unroll
    for (int tt = 0; tt < 2; ++tt)
        #pragma unroll
        for (int cb = 0; cb < 8; ++cb) acc[tt][cb] = (f32x4){0.f, 0.f, 0.f, 0.f};
    float m_run[2] = {-INFINITY, -INFINITY};
    float l_run[2] = {0.f, 0.f};

    for (int m0 = 0; m0 < N; m0 += 64) {
        __syncthreads();
        // stage K tile (swizzled source -> linear LDS dest; read-side applies same XOR)
        #pragma unroll
        for (int k = 0; k < 8; ++k) {
            int D = w * 8192 + k * 1024 + lane * 16;
            int row = D >> 8, colb = D & 255;
            gload_lds16(xb + (size_t)(m0 + row) * 256 + (colb ^ ((row & 15) << 4)),
                        lds + w * 8192 + k * 1024);
        }
        // stage V^T tile
        #pragma unroll
        for (int k = 0; k < 8; ++k) {
            int D = w * 8192 + k * 1024 + lane * 16;
            int c = D >> 7, colb = D & 127;
            gload_lds16(xtb + (size_t)c * (2 * N) + m0 * 2 + (colb ^ ((c & 7) << 4)),
                        lds + 16384 + w * 8192 + k * 1024);
        }
        __syncthreads();

        // ---- QK^T (S^T): A = K rows (permuted), B = Q
        f32x4 accS[2][4];
        #pragma unroll
        for (int tt = 0; tt < 2; ++tt)
            #pragma unroll
            for (int mb = 0; mb < 4; ++mb) accS[tt][mb] = (f32x4){0.f, 0.f, 0.f, 0.f};
        #pragma unroll
        for (int mb = 0; mb < 4; ++mb) {
            const int rowm = ((mb >> 1) << 5) + ((mb & 1) << 2) + ((rho >> 2) << 3) + (rho & 3);
            const char* kb = lds + rowm * 256;
            const int swz = (rowm & 15) << 4;
            #pragma unroll
            for (int kc = 0; kc < 4; ++kc) {
                bf16x8 kf = *(const bf16x8*)(kb + ((kc * 64 + g * 16) ^ swz));
                accS[0][mb] = __builtin_amdgcn_mfma_f32_16x16x32_bf16(kf, qf[0][kc], accS[0][mb], 0, 0, 0);
                accS[1][mb] = __builtin_amdgcn_mfma_f32_16x16x32_bf16(kf, qf[1][kc], accS[1][mb], 0, 0, 0);
            }
        }

        // ---- online softmax (per-lane: n = rho) + pack P^T into PV B-frags
        bf16x8 pb[2][2];
        #pragma unroll
        for (int tt = 0; tt < 2; ++tt) {
            float tm = accS[tt][0][0];
            #pragma unroll
            for (int mb = 0; mb < 4; ++mb)
                #pragma unroll
                for (int r = 0; r < 4; ++r) tm = fmaxf(tm, accS[tt][mb][r]);
            tm = fmaxf(tm, __shfl_xor(tm, 16));
            tm = fmaxf(tm, __shfl_xor(tm, 32));
            float nm = fmaxf(m_run[tt], tm);
            float sc = __expf(m_run[tt] - nm);
            m_run[tt] = nm;
            float ts = 0.f;
            float p[4][4];
            #pragma unroll
            for (int mb = 0; mb < 4; ++mb)
                #pragma unroll
                for (int r = 0; r < 4; ++r) {
                    p[mb][r] = __expf(accS[tt][mb][r] - nm);
                    ts += p[mb][r];
                }
            ts += __shfl_xor(ts, 16);
            ts += __shfl_xor(ts, 32);
            l_run[tt] = l_run[tt] * sc + ts;
            #pragma unroll
            for (int cb = 0; cb < 8; ++cb) {
                acc[tt][cb][0] *= sc; acc[tt][cb][1] *= sc;
                acc[tt][cb][2] *= sc; acc[tt][cb][3] *= sc;
            }
            #pragma unroll
            for (int ks = 0; ks < 2; ++ks) {
                bf16x8 v;
                #pragma unroll
                for (int r = 0; r < 4; ++r) {
                    v[r]     = (short)f2bf(p[2 * ks][r]);       // m = 32ks + 8g + r
                    v[4 + r] = (short)f2bf(p[2 * ks + 1][r]);   // m = 32ks + 8g + 4 + r
                }
                pb[tt][ks] = v;
            }
        }

        // ---- PV: A = V^T rows (c), B = P^T (regs)
        const char* vb0 = lds + 16384;
        #pragma unroll
        for (int cb = 0; cb < 8; ++cb) {
            const int c = cb * 16 + rho;
            const char* vb = vb0 + c * 128;
            const int vswz = (c & 7) << 4;
            #pragma unroll
            for (int ks = 0; ks < 2; ++ks) {
                bf16x8 vf = *(const bf16x8*)(vb + ((ks * 64 + g * 16) ^ vswz));
                acc[0][cb] = __builtin_amdgcn_mfma_f32_16x16x32_bf16(vf, pb[0][ks], acc[0][cb], 0, 0, 0);
                acc[1][cb] = __builtin_amdgcn_mfma_f32_16x16x32_bf16(vf, pb[1][ks], acc[1][cb], 0, 0, 0);
            }
        }
    }

    // epilogue: D layout col = rho = n-local, row = 4g + r = c-local
    #pragma unroll
    for (int tt = 0; tt < 2; ++tt) {
        float invl = 1.0f / l_run[tt];
        int n = n0 + w * 32 + tt * 16 + rho;
        #pragma unroll
        for (int cb = 0; cb < 8; ++cb)
            #pragma unroll
            for (int r = 0; r < 4; ++r)
                out[((size_t)b * C_ + cb * 16 + g * 4 + r) * N + n] = acc[tt][cb][r] * invl;
    }
}

// ---------------- bilinear upsample (half-pixel centers, clamp) + sum
template<int HS>
__device__ __forceinline__ float bilin(const float* __restrict__ a, int h, int w) {
    constexpr float sc = (float)HS / 64.0f;
    float sh = (h + 0.5f) * sc - 0.5f;
    float sw = (w + 0.5f) * sc - 0.5f;
    int h0 = (int)floorf(sh); float fh = sh - (float)h0;
    int w0 = (int)floorf(sw); float fw = sw - (float)w0;
    int h0c = max(h0, 0), h1c = min(h0 + 1, HS - 1);
    int w0c = max(w0, 0), w1c = min(w0 + 1, HS - 1);
    float v00 = a[h0c * HS + w0c], v01 = a[h0c * HS + w1c];
    float v10 = a[h1c * HS + w0c], v11 = a[h1c * HS + w1c];
    return (1.f - fh) * ((1.f - fw) * v00 + fw * v01)
         +        fh  * ((1.f - fw) * v10 + fw * v11);
}

__global__ __launch_bounds__(256) void combine_kernel(float* __restrict__ out,
                                                      const float* __restrict__ att2,
                                                      const float* __restrict__ att4) {
    int e = blockIdx.x * 256 + threadIdx.x;
    if (e >= B_ * C_ * 64 * 64) return;
    int w  = e & 63;
    int h  = (e >> 6) & 63;
    int bc = e >> 12;
    float v = out[e];
    v += bilin<32>(att2 + (size_t)bc * 1024, h, w);
    v += bilin<16>(att4 + (size_t)bc * 256,  h, w);
    out[e] = v;
}

extern "C" void kernel_launch(void* const* d_in, const int* in_sizes, int n_in,
                              void* d_out, int out_size, void* d_ws, size_t ws_size,
                              hipStream_t stream) {
    const float* x = (const float*)d_in[0];
    float* out = (float*)d_out;
    char* ws = (char*)d_ws;
    unsigned short* xt1  = (unsigned short*)(ws + XT1_B);
    unsigned short* xt2  = (unsigned short*)(ws + XT2_B);
    unsigned short* xt4  = (unsigned short*)(ws + XT4_B);
    unsigned short* xtT1 = (unsigned short*)(ws + XTT1_B);
    unsigned short* xtT2 = (unsigned short*)(ws + XTT2_B);
    unsigned short* xtT4 = (unsigned short*)(ws + XTT4_B);
    float* att2 = (float*)(ws + ATT2_B);
    float* att4 = (float*)(ws + ATT4_B);

    pool_tr<1><<<dim3(64, 4, B_), 256, 0, stream>>>(x, xt1, xtT1);
    pool_tr<2><<<dim3(32, 4, B_), 256, 0, stream>>>(x, xt2, xtT2);
    pool_tr<4><<<dim3(16, 4, B_), 256, 0, stream>>>(x, xt4, xtT4);

    attn_mfma<4096><<<dim3(64, B_), 128, 0, stream>>>(xt1, xtT1, out);
    attn_mfma<1024><<<dim3(16, B_), 128, 0, stream>>>(xt2, xtT2, att2);
    attn_mfma<256 ><<<dim3(4,  B_), 128, 0, stream>>>(xt4, xtT4, att4);

    combine_kernel<<<(B_ * C_ * 64 * 64 + 255) / 256, 256, 0, stream>>>(out, att2, att4);
}

// Round 3
// 149.725 us; speedup vs baseline: 9.4273x; 1.3842x over previous
//
#include <hip/hip_runtime.h>
#include <hip/hip_bf16.h>
#include <math.h>

typedef __attribute__((ext_vector_type(8))) short bf16x8;
typedef __attribute__((ext_vector_type(4))) float f32x4;

#define B_ 4
#define C_ 128

// ---- workspace byte offsets ----
#define XT1_B   0ull
#define XT2_B   4194304ull
#define XT4_B   5242880ull
#define XTT1_B  5505024ull
#define XTT2_B  9699328ull
#define XTT4_B  10747904ull
#define ATT2_B  11010048ull
#define ATT4_B  13107200ull

__device__ __forceinline__ unsigned short f2bf(float f) {
    unsigned int u = __builtin_bit_cast(unsigned int, f);
    return (unsigned short)((u + 0x7FFFu + ((u >> 16) & 1u)) >> 16);
}

__device__ __forceinline__ void gload_lds16(const void* g, void* l) {
    __builtin_amdgcn_global_load_lds(
        (const __attribute__((address_space(1))) unsigned int*)g,
        (__attribute__((address_space(3))) unsigned int*)l, 16, 0, 0);
}

// ---------------- pool + transpose: x[B][C][64][64] -> xt[B][N][C] bf16, xtT[B][C][N] bf16
template<int S>
__global__ __launch_bounds__(256) void pool_tr(const float* __restrict__ x,
                                               unsigned short* __restrict__ xt,
                                               unsigned short* __restrict__ xtT) {
    constexpr int WS = 64 / S;
    constexpr int N  = WS * WS;
    constexpr int RS = S * 64 + 1;
    __shared__ float lds[32 * RS];
    const int hp = blockIdx.x;
    const int c0 = blockIdx.y * 32;
    const int b  = blockIdx.z;
    const int t  = threadIdx.x;

    for (int e = t; e < 32 * S * 64; e += 256) {
        int ci  = e / (S * 64);
        int rem = e - ci * (S * 64);
        lds[ci * RS + rem] =
            x[((size_t)(b * C_ + c0 + ci) * 64 + (hp * S + (rem >> 6))) * 64 + (rem & 63)];
    }
    __syncthreads();

    constexpr float inv = 1.0f / (S * S);
    for (int v = t; v < 32 * WS; v += 256) {
        int ci = v & 31, wp = v >> 5;
        float s = 0.f;
        #pragma unroll
        for (int i = 0; i < S; ++i)
            #pragma unroll
            for (int j = 0; j < S; ++j) s += lds[ci * RS + i * 64 + wp * S + j];
        xt[((size_t)b * N + hp * WS + wp) * C_ + c0 + ci] = f2bf(s * inv);
    }
    for (int v = t; v < 32 * WS; v += 256) {
        int wp = v & (WS - 1), ci = v / WS;
        float s = 0.f;
        #pragma unroll
        for (int i = 0; i < S; ++i)
            #pragma unroll
            for (int j = 0; j < S; ++j) s += lds[ci * RS + i * 64 + wp * S + j];
        xtT[((size_t)(b * C_ + c0 + ci)) * N + hp * WS + wp] = f2bf(s * inv);
    }
}

// ---------------- MFMA flash attention, 2-phase prefetch pipeline
// QW waves/block, 16 q-rows per wave. KV tile = 64 rows, double-buffered.
template<int N, int QW>
__global__ __launch_bounds__(64 * QW) void attn_mfma(const unsigned short* __restrict__ xt,
                                                     const unsigned short* __restrict__ xtT,
                                                     float* __restrict__ out) {
    __shared__ char lds[65536];          // 2 bufs x (K [64][128]bf16 16K + V^T [128][64]bf16 16K)
    // XCD remap: 8 XCDs round-robin on linear bid; give each XCD pair one batch
    // so per-XCD staging working set = xt+xtT of one batch (4 MB = one L2).
    const int bid  = blockIdx.x + gridDim.x * blockIdx.y;
    const int xcd  = bid & 7;
    const int slot = bid >> 3;
    const int b    = xcd >> 1;
    const int qx   = (xcd & 1) * (gridDim.x >> 1) + slot;
    const int n0   = qx * (16 * QW);

    const int tid = threadIdx.x;
    const int w = tid >> 6, lane = tid & 63;
    const int g = lane >> 4, rho = lane & 15;

    const char* xb  = (const char*)(xt  + (size_t)b * N * C_);
    const char* xtb = (const char*)(xtT + (size_t)b * C_ * N);

    // Q fragments (B-operand of S^T mfma)
    bf16x8 qf[4];
    {
        const char* qr = xb + (size_t)(n0 + w * 16 + rho) * 256;
        #pragma unroll
        for (int kc = 0; kc < 4; ++kc) qf[kc] = *(const bf16x8*)(qr + kc * 64 + g * 16);
    }

    constexpr int LPW = 16 / QW;         // gload_lds per wave per operand
    auto stage = [&](int buf, int m0) {
        #pragma unroll
        for (int k = 0; k < LPW; ++k) {
            int D = (w * LPW + k) * 1024 + lane * 16;
            int row = D >> 8, colb = D & 255;
            gload_lds16(xb + (size_t)(m0 + row) * 256 + (colb ^ ((row & 15) << 4)),
                        lds + buf * 32768 + (w * LPW + k) * 1024);
        }
        #pragma unroll
        for (int k = 0; k < LPW; ++k) {
            int D = (w * LPW + k) * 1024 + lane * 16;
            int c = D >> 7, colb = D & 127;
            gload_lds16(xtb + (size_t)c * (2 * N) + m0 * 2 + (colb ^ ((c & 7) << 4)),
                        lds + buf * 32768 + 16384 + (w * LPW + k) * 1024);
        }
    };

    f32x4 acc[8];
    #pragma unroll
    for (int cb = 0; cb < 8; ++cb) acc[cb] = (f32x4){0.f, 0.f, 0.f, 0.f};
    float m_run = -INFINITY, l_run = 0.f;

    // prologue: stage tile 0
    stage(0, 0);
    asm volatile("s_waitcnt vmcnt(0)" ::: "memory");
    __syncthreads();

    constexpr int NT = N / 64;
    for (int t = 0; t < NT; ++t) {
        const int cur = t & 1;
        if (t + 1 < NT) stage(cur ^ 1, (t + 1) * 64);   // prefetch next tile
        __builtin_amdgcn_sched_barrier(0);

        const char* kbuf = lds + cur * 32768;
        const char* vbuf = kbuf + 16384;

        // ---- QK^T (S^T): A = K rows (permuted m-tiles), B = Q
        f32x4 accS[4];
        #pragma unroll
        for (int mb = 0; mb < 4; ++mb) accS[mb] = (f32x4){0.f, 0.f, 0.f, 0.f};
        #pragma unroll
        for (int mb = 0; mb < 4; ++mb) {
            const int rowm = ((mb >> 1) << 5) + ((mb & 1) << 2) + ((rho >> 2) << 3) + (rho & 3);
            const char* kb = kbuf + rowm * 256;
            const int swz = (rowm & 15) << 4;
            #pragma unroll
            for (int kc = 0; kc < 4; ++kc) {
                bf16x8 kf = *(const bf16x8*)(kb + ((kc * 64 + g * 16) ^ swz));
                accS[mb] = __builtin_amdgcn_mfma_f32_16x16x32_bf16(kf, qf[kc], accS[mb], 0, 0, 0);
            }
        }

        // ---- online softmax (per-lane n = rho; reduce over g via shfl 16/32)
        float tm = accS[0][0];
        #pragma unroll
        for (int mb = 0; mb < 4; ++mb)
            #pragma unroll
            for (int r = 0; r < 4; ++r) tm = fmaxf(tm, accS[mb][r]);
        tm = fmaxf(tm, __shfl_xor(tm, 16));
        tm = fmaxf(tm, __shfl_xor(tm, 32));
        float nm = fmaxf(m_run, tm);
        float sc = __expf(m_run - nm);
        m_run = nm;
        float ts = 0.f;
        float p[4][4];
        #pragma unroll
        for (int mb = 0; mb < 4; ++mb)
            #pragma unroll
            for (int r = 0; r < 4; ++r) { p[mb][r] = __expf(accS[mb][r] - nm); ts += p[mb][r]; }
        ts += __shfl_xor(ts, 16);
        ts += __shfl_xor(ts, 32);
        l_run = l_run * sc + ts;
        #pragma unroll
        for (int cb = 0; cb < 8; ++cb) {
            acc[cb][0] *= sc; acc[cb][1] *= sc; acc[cb][2] *= sc; acc[cb][3] *= sc;
        }
        bf16x8 pb[2];
        #pragma unroll
        for (int ks = 0; ks < 2; ++ks) {
            bf16x8 v;
            #pragma unroll
            for (int r = 0; r < 4; ++r) {
                v[r]     = (short)f2bf(p[2 * ks][r]);
                v[4 + r] = (short)f2bf(p[2 * ks + 1][r]);
            }
            pb[ks] = v;
        }

        // ---- PV: A = V^T rows (c), B = P^T (regs)
        #pragma unroll
        for (int cb = 0; cb < 8; ++cb) {
            const int c = cb * 16 + rho;
            const char* vb = vbuf + c * 128;
            const int vswz = (c & 7) << 4;
            #pragma unroll
            for (int ks = 0; ks < 2; ++ks) {
                bf16x8 vf = *(const bf16x8*)(vb + ((ks * 64 + g * 16) ^ vswz));
                acc[cb] = __builtin_amdgcn_mfma_f32_16x16x32_bf16(vf, pb[ks], acc[cb], 0, 0, 0);
            }
        }

        if (t + 1 < NT) {
            asm volatile("s_waitcnt vmcnt(0)" ::: "memory");   // next tile staged
            __syncthreads();                                    // all waves done w/ cur
        }
    }

    // epilogue: D col = rho (n-local), row = 4g + r (c-local)
    const float invl = 1.0f / l_run;
    const int n = n0 + w * 16 + rho;
    #pragma unroll
    for (int cb = 0; cb < 8; ++cb)
        #pragma unroll
        for (int r = 0; r < 4; ++r)
            out[((size_t)b * C_ + cb * 16 + g * 4 + r) * N + n] = acc[cb][r] * invl;
}

// ---------------- bilinear upsample (half-pixel centers, clamp) + sum
template<int HS>
__device__ __forceinline__ float bilin(const float* __restrict__ a, int h, int w) {
    constexpr float sc = (float)HS / 64.0f;
    float sh = (h + 0.5f) * sc - 0.5f;
    float sw = (w + 0.5f) * sc - 0.5f;
    int h0 = (int)floorf(sh); float fh = sh - (float)h0;
    int w0 = (int)floorf(sw); float fw = sw - (float)w0;
    int h0c = max(h0, 0), h1c = min(h0 + 1, HS - 1);
    int w0c = max(w0, 0), w1c = min(w0 + 1, HS - 1);
    float v00 = a[h0c * HS + w0c], v01 = a[h0c * HS + w1c];
    float v10 = a[h1c * HS + w0c], v11 = a[h1c * HS + w1c];
    return (1.f - fh) * ((1.f - fw) * v00 + fw * v01)
         +        fh  * ((1.f - fw) * v10 + fw * v11);
}

__global__ __launch_bounds__(256) void combine_kernel(float* __restrict__ out,
                                                      const float* __restrict__ att2,
                                                      const float* __restrict__ att4) {
    int e = blockIdx.x * 256 + threadIdx.x;
    if (e >= B_ * C_ * 64 * 64) return;
    int w  = e & 63;
    int h  = (e >> 6) & 63;
    int bc = e >> 12;
    float v = out[e];
    v += bilin<32>(att2 + (size_t)bc * 1024, h, w);
    v += bilin<16>(att4 + (size_t)bc * 256,  h, w);
    out[e] = v;
}

extern "C" void kernel_launch(void* const* d_in, const int* in_sizes, int n_in,
                              void* d_out, int out_size, void* d_ws, size_t ws_size,
                              hipStream_t stream) {
    const float* x = (const float*)d_in[0];
    float* out = (float*)d_out;
    char* ws = (char*)d_ws;
    unsigned short* xt1  = (unsigned short*)(ws + XT1_B);
    unsigned short* xt2  = (unsigned short*)(ws + XT2_B);
    unsigned short* xt4  = (unsigned short*)(ws + XT4_B);
    unsigned short* xtT1 = (unsigned short*)(ws + XTT1_B);
    unsigned short* xtT2 = (unsigned short*)(ws + XTT2_B);
    unsigned short* xtT4 = (unsigned short*)(ws + XTT4_B);
    float* att2 = (float*)(ws + ATT2_B);
    float* att4 = (float*)(ws + ATT4_B);

    pool_tr<1><<<dim3(64, 4, B_), 256, 0, stream>>>(x, xt1, xtT1);
    pool_tr<2><<<dim3(32, 4, B_), 256, 0, stream>>>(x, xt2, xtT2);
    pool_tr<4><<<dim3(16, 4, B_), 256, 0, stream>>>(x, xt4, xtT4);

    attn_mfma<4096, 4><<<dim3(64, 4), 256, 0, stream>>>(xt1, xtT1, out);
    attn_mfma<1024, 2><<<dim3(32, 4), 128, 0, stream>>>(xt2, xtT2, att2);
    attn_mfma<256,  1><<<dim3(16, 4),  64, 0, stream>>>(xt4, xtT4, att4);

    combine_kernel<<<(B_ * C_ * 64 * 64 + 255) / 256, 256, 0, stream>>>(out, att2, att4);
}

// Round 4
// 105.249 us; speedup vs baseline: 13.4110x; 1.4226x over previous
//
#include <hip/hip_runtime.h>
#include <hip/hip_bf16.h>
#include <math.h>

typedef __attribute__((ext_vector_type(8))) short bf16x8;
typedef __attribute__((ext_vector_type(4))) float f32x4;

#define B_ 4
#define C_ 128

// ---- workspace byte offsets (MB = 1048576) ----
#define XT1_B   0ull              // bf16 [4][4096][128]   4 MB
#define XT2_B   4194304ull        // bf16 [4][1024][128]   1 MB
#define XT4_B   5242880ull        // bf16 [4][256][128]    0.25 MB
#define XTT1_B  5505024ull        // bf16 [4][128][4096]   4 MB
#define XTT2_B  9699328ull        // bf16 [4][128][1024]   1 MB
#define XTT4_B  10747904ull       // bf16 [4][128][256]    0.25 MB
#define O1P_B   11010048ull       // bf16 [2][4][128][4096] 8 MB (unnormalized partials)
#define ML1_B   19398656ull       // f32  [2][4][4096][2]  256 KB
#define A2P_B   19660800ull       // bf16 [4][4][128][1024] 4 MB
#define ML2_B   23855104ull       // f32  [4][4][1024][2]  128 KB
#define A4P_B   23986176ull       // bf16 [4][4][128][256] 1 MB
#define ML4_B   25034752ull       // f32  [4][4][256][2]   32 KB
#define A2M_B   25165824ull       // bf16 [4][128][1024]   1 MB (merged)
#define A4M_B   26214400ull       // bf16 [4][128][256]    0.25 MB (merged)
// total 26,476,544 bytes ≈ 25.25 MB

__device__ __forceinline__ unsigned short f2bf(float f) {
    unsigned int u = __builtin_bit_cast(unsigned int, f);
    return (unsigned short)((u + 0x7FFFu + ((u >> 16) & 1u)) >> 16);
}
__device__ __forceinline__ float bf2f(unsigned short u) {
    unsigned int x = ((unsigned int)u) << 16;
    return __builtin_bit_cast(float, x);
}

__device__ __forceinline__ void gload_lds16(const void* g, void* l) {
    __builtin_amdgcn_global_load_lds(
        (const __attribute__((address_space(1))) unsigned int*)g,
        (__attribute__((address_space(3))) unsigned int*)l, 16, 0, 0);
}

// ---------------- pool + transpose: x[B][C][64][64] -> xt[B][N][C] bf16, xtT[B][C][N] bf16
template<int S>
__global__ __launch_bounds__(256) void pool_tr(const float* __restrict__ x,
                                               unsigned short* __restrict__ xt,
                                               unsigned short* __restrict__ xtT) {
    constexpr int WS = 64 / S;
    constexpr int N  = WS * WS;
    constexpr int RS = S * 64 + 1;
    __shared__ float lds[32 * RS];
    const int hp = blockIdx.x;
    const int c0 = blockIdx.y * 32;
    const int b  = blockIdx.z;
    const int t  = threadIdx.x;

    for (int e = t; e < 32 * S * 64; e += 256) {
        int ci  = e / (S * 64);
        int rem = e - ci * (S * 64);
        lds[ci * RS + rem] =
            x[((size_t)(b * C_ + c0 + ci) * 64 + (hp * S + (rem >> 6))) * 64 + (rem & 63)];
    }
    __syncthreads();

    constexpr float inv = 1.0f / (S * S);
    for (int v = t; v < 32 * WS; v += 256) {
        int ci = v & 31, wp = v >> 5;
        float s = 0.f;
        #pragma unroll
        for (int i = 0; i < S; ++i)
            #pragma unroll
            for (int j = 0; j < S; ++j) s += lds[ci * RS + i * 64 + wp * S + j];
        xt[((size_t)b * N + hp * WS + wp) * C_ + c0 + ci] = f2bf(s * inv);
    }
    for (int v = t; v < 32 * WS; v += 256) {
        int wp = v & (WS - 1), ci = v / WS;
        float s = 0.f;
        #pragma unroll
        for (int i = 0; i < S; ++i)
            #pragma unroll
            for (int j = 0; j < S; ++j) s += lds[ci * RS + i * 64 + wp * S + j];
        xtT[((size_t)(b * C_ + c0 + ci)) * N + hp * WS + wp] = f2bf(s * inv);
    }
}

// ---------------- MFMA flash attention, 2-phase pipeline + KV-split partials
// 4 waves/block, 16 q-rows per wave (QBLK=64). Each block covers KV rows
// [split*N/SPLIT, (split+1)*N/SPLIT). Writes UNNORMALIZED acc (bf16) + m,l (f32).
template<int N, int SPLIT>
__global__ __launch_bounds__(256) void attn_mfma(const unsigned short* __restrict__ xt,
                                                 const unsigned short* __restrict__ xtT,
                                                 unsigned short* __restrict__ op,
                                                 float* __restrict__ ml) {
    __shared__ char lds[65536];          // 2 bufs x (K [64][128]bf16 + V^T [128][64]bf16)
    constexpr int LOG2S = (SPLIT == 2) ? 1 : 2;
    constexpr int W2    = (N / 64) * SPLIT / 2;   // work items per XCD
    // XCD remap: xcd = bid&7 (round-robin dispatch), batch pinned to an XCD pair
    // so per-XCD staging working set = one batch's xt+xtT (<=4MB, L2-resident).
    const int bid   = blockIdx.x;
    const int xcd   = bid & 7;
    const int b     = xcd >> 1;
    const int wi    = (xcd & 1) * W2 + (bid >> 3);
    const int split = wi & (SPLIT - 1);
    const int qx    = wi >> LOG2S;
    const int n0    = qx * 64;
    const int m_beg = split * (N / SPLIT);
    constexpr int NT = N / SPLIT / 64;

    const int tid = threadIdx.x;
    const int w = tid >> 6, lane = tid & 63;
    const int g = lane >> 4, rho = lane & 15;

    const char* xb  = (const char*)(xt  + (size_t)b * N * C_);
    const char* xtb = (const char*)(xtT + (size_t)b * C_ * N);

    // Q fragments (B-operand of S^T mfma)
    bf16x8 qf[4];
    {
        const char* qr = xb + (size_t)(n0 + w * 16 + rho) * 256;
        #pragma unroll
        for (int kc = 0; kc < 4; ++kc) qf[kc] = *(const bf16x8*)(qr + kc * 64 + g * 16);
    }

    auto stage = [&](int buf, int m0) {
        #pragma unroll
        for (int k = 0; k < 4; ++k) {
            int D = (w * 4 + k) * 1024 + lane * 16;
            int row = D >> 8, colb = D & 255;
            gload_lds16(xb + (size_t)(m0 + row) * 256 + (colb ^ ((row & 15) << 4)),
                        lds + buf * 32768 + (w * 4 + k) * 1024);
        }
        #pragma unroll
        for (int k = 0; k < 4; ++k) {
            int D = (w * 4 + k) * 1024 + lane * 16;
            int c = D >> 7, colb = D & 127;
            gload_lds16(xtb + (size_t)c * (2 * N) + m0 * 2 + (colb ^ ((c & 7) << 4)),
                        lds + buf * 32768 + 16384 + (w * 4 + k) * 1024);
        }
    };

    f32x4 acc[8];
    #pragma unroll
    for (int cb = 0; cb < 8; ++cb) acc[cb] = (f32x4){0.f, 0.f, 0.f, 0.f};
    float m_run = -INFINITY, l_run = 0.f;

    stage(0, m_beg);
    asm volatile("s_waitcnt vmcnt(0)" ::: "memory");
    __syncthreads();

    for (int t = 0; t < NT; ++t) {
        const int cur = t & 1;
        if (t + 1 < NT) stage(cur ^ 1, m_beg + (t + 1) * 64);
        __builtin_amdgcn_sched_barrier(0);

        const char* kbuf = lds + cur * 32768;
        const char* vbuf = kbuf + 16384;

        // ---- QK^T (S^T): A = K rows (permuted m-tiles), B = Q
        f32x4 accS[4];
        #pragma unroll
        for (int mb = 0; mb < 4; ++mb) accS[mb] = (f32x4){0.f, 0.f, 0.f, 0.f};
        #pragma unroll
        for (int mb = 0; mb < 4; ++mb) {
            const int rowm = ((mb >> 1) << 5) + ((mb & 1) << 2) + ((rho >> 2) << 3) + (rho & 3);
            const char* kb = kbuf + rowm * 256;
            const int swz = (rowm & 15) << 4;
            #pragma unroll
            for (int kc = 0; kc < 4; ++kc) {
                bf16x8 kf = *(const bf16x8*)(kb + ((kc * 64 + g * 16) ^ swz));
                accS[mb] = __builtin_amdgcn_mfma_f32_16x16x32_bf16(kf, qf[kc], accS[mb], 0, 0, 0);
            }
        }

        // ---- online softmax, T13 defer-max (tau=4): skip rescale when tile max small
        float tm = accS[0][0];
        #pragma unroll
        for (int mb = 0; mb < 4; ++mb)
            #pragma unroll
            for (int r = 0; r < 4; ++r) tm = fmaxf(tm, accS[mb][r]);
        tm = fmaxf(tm, __shfl_xor(tm, 16));
        tm = fmaxf(tm, __shfl_xor(tm, 32));
        if (!__all(tm <= m_run + 4.0f)) {
            float nm = fmaxf(m_run, tm);
            float sc = __expf(m_run - nm);      // exp(-inf)=0 on first tile
            l_run *= sc;
            m_run = nm;
            #pragma unroll
            for (int cb = 0; cb < 8; ++cb) {
                acc[cb][0] *= sc; acc[cb][1] *= sc; acc[cb][2] *= sc; acc[cb][3] *= sc;
            }
        }
        float ts = 0.f;
        float p[4][4];
        #pragma unroll
        for (int mb = 0; mb < 4; ++mb)
            #pragma unroll
            for (int r = 0; r < 4; ++r) { p[mb][r] = __expf(accS[mb][r] - m_run); ts += p[mb][r]; }
        ts += __shfl_xor(ts, 16);
        ts += __shfl_xor(ts, 32);
        l_run += ts;
        bf16x8 pb[2];
        #pragma unroll
        for (int ks = 0; ks < 2; ++ks) {
            bf16x8 v;
            #pragma unroll
            for (int r = 0; r < 4; ++r) {
                v[r]     = (short)f2bf(p[2 * ks][r]);
                v[4 + r] = (short)f2bf(p[2 * ks + 1][r]);
            }
            pb[ks] = v;
        }

        // ---- PV: A = V^T rows (c), B = P^T (regs)
        #pragma unroll
        for (int cb = 0; cb < 8; ++cb) {
            const int c = cb * 16 + rho;
            const char* vb = vbuf + c * 128;
            const int vswz = (c & 7) << 4;
            #pragma unroll
            for (int ks = 0; ks < 2; ++ks) {
                bf16x8 vf = *(const bf16x8*)(vb + ((ks * 64 + g * 16) ^ vswz));
                acc[cb] = __builtin_amdgcn_mfma_f32_16x16x32_bf16(vf, pb[ks], acc[cb], 0, 0, 0);
            }
        }

        if (t + 1 < NT) {
            asm volatile("s_waitcnt vmcnt(0)" ::: "memory");
            __syncthreads();
        }
    }

    // epilogue: UNNORMALIZED partial + (m,l). D col = rho (n-local), row = 4g+r (c-local)
    const int n = n0 + w * 16 + rho;
    #pragma unroll
    for (int cb = 0; cb < 8; ++cb)
        #pragma unroll
        for (int r = 0; r < 4; ++r)
            op[((size_t)(split * B_ + b) * C_ + cb * 16 + g * 4 + r) * N + n] = f2bf(acc[cb][r]);
    if (g == 0) {
        ml[((size_t)(split * B_ + b) * N + n) * 2 + 0] = m_run;
        ml[((size_t)(split * B_ + b) * N + n) * 2 + 1] = l_run;
    }
}

// ---------------- merge 4-way partials for scales 2 and 4
__global__ __launch_bounds__(256) void merge_small(const unsigned short* __restrict__ a2p,
                                                   const float* __restrict__ ml2,
                                                   const unsigned short* __restrict__ a4p,
                                                   const float* __restrict__ ml4,
                                                   unsigned short* __restrict__ a2m,
                                                   unsigned short* __restrict__ a4m) {
    int idx = blockIdx.x * 256 + threadIdx.x;
    if (idx < 4 * 128 * 1024) {
        int n = idx & 1023, c = (idx >> 10) & 127, b = idx >> 17;
        float M = -INFINITY;
        #pragma unroll
        for (int s = 0; s < 4; ++s) M = fmaxf(M, ml2[((s * 4 + b) * 1024 + n) * 2]);
        float L = 0.f, O = 0.f;
        #pragma unroll
        for (int s = 0; s < 4; ++s) {
            float wgt = __expf(ml2[((s * 4 + b) * 1024 + n) * 2] - M);
            L += ml2[((s * 4 + b) * 1024 + n) * 2 + 1] * wgt;
            O += bf2f(a2p[((size_t)((s * 4 + b) * 128 + c)) * 1024 + n]) * wgt;
        }
        a2m[((size_t)(b * 128 + c)) * 1024 + n] = f2bf(O / L);
    } else {
        int i2 = idx - 4 * 128 * 1024;
        if (i2 < 4 * 128 * 256) {
            int n = i2 & 255, c = (i2 >> 8) & 127, b = i2 >> 15;
            float M = -INFINITY;
            #pragma unroll
            for (int s = 0; s < 4; ++s) M = fmaxf(M, ml4[((s * 4 + b) * 256 + n) * 2]);
            float L = 0.f, O = 0.f;
            #pragma unroll
            for (int s = 0; s < 4; ++s) {
                float wgt = __expf(ml4[((s * 4 + b) * 256 + n) * 2] - M);
                L += ml4[((s * 4 + b) * 256 + n) * 2 + 1] * wgt;
                O += bf2f(a4p[((size_t)((s * 4 + b) * 128 + c)) * 256 + n]) * wgt;
            }
            a4m[((size_t)(b * 128 + c)) * 256 + n] = f2bf(O / L);
        }
    }
}

// ---------------- bilinear upsample (half-pixel centers, clamp) from bf16 grid
template<int HS>
__device__ __forceinline__ float bilin(const unsigned short* __restrict__ a, int h, int w) {
    constexpr float sc = (float)HS / 64.0f;
    float sh = (h + 0.5f) * sc - 0.5f;
    float sw = (w + 0.5f) * sc - 0.5f;
    int h0 = (int)floorf(sh); float fh = sh - (float)h0;
    int w0 = (int)floorf(sw); float fw = sw - (float)w0;
    int h0c = max(h0, 0), h1c = min(h0 + 1, HS - 1);
    int w0c = max(w0, 0), w1c = min(w0 + 1, HS - 1);
    float v00 = bf2f(a[h0c * HS + w0c]), v01 = bf2f(a[h0c * HS + w1c]);
    float v10 = bf2f(a[h1c * HS + w0c]), v11 = bf2f(a[h1c * HS + w1c]);
    return (1.f - fh) * ((1.f - fw) * v00 + fw * v01)
         +        fh  * ((1.f - fw) * v10 + fw * v11);
}

// ---------------- scale-1 2-way merge + upsampled adds
__global__ __launch_bounds__(256) void combine_kernel(float* __restrict__ out,
                                                      const unsigned short* __restrict__ o1p,
                                                      const float* __restrict__ ml1,
                                                      const unsigned short* __restrict__ a2m,
                                                      const unsigned short* __restrict__ a4m) {
    int e = blockIdx.x * 256 + threadIdx.x;
    if (e >= B_ * C_ * 64 * 64) return;
    int w  = e & 63;
    int h  = (e >> 6) & 63;
    int bc = e >> 12;
    int b  = bc >> 7;
    int n  = (h << 6) | w;
    float m0 = ml1[((size_t)b * 4096 + n) * 2],       l0 = ml1[((size_t)b * 4096 + n) * 2 + 1];
    float m1 = ml1[((size_t)(4 + b) * 4096 + n) * 2], l1 = ml1[((size_t)(4 + b) * 4096 + n) * 2 + 1];
    float M  = fmaxf(m0, m1);
    float w0 = __expf(m0 - M), w1 = __expf(m1 - M);
    float num = bf2f(o1p[(size_t)bc * 4096 + n]) * w0
              + bf2f(o1p[((size_t)(512 + bc)) * 4096 + n]) * w1;
    float den = l0 * w0 + l1 * w1;
    float v = num / den;
    v += bilin<32>(a2m + (size_t)bc * 1024, h, w);
    v += bilin<16>(a4m + (size_t)bc * 256,  h, w);
    out[e] = v;
}

extern "C" void kernel_launch(void* const* d_in, const int* in_sizes, int n_in,
                              void* d_out, int out_size, void* d_ws, size_t ws_size,
                              hipStream_t stream) {
    const float* x = (const float*)d_in[0];
    float* out = (float*)d_out;
    char* ws = (char*)d_ws;
    unsigned short* xt1  = (unsigned short*)(ws + XT1_B);
    unsigned short* xt2  = (unsigned short*)(ws + XT2_B);
    unsigned short* xt4  = (unsigned short*)(ws + XT4_B);
    unsigned short* xtT1 = (unsigned short*)(ws + XTT1_B);
    unsigned short* xtT2 = (unsigned short*)(ws + XTT2_B);
    unsigned short* xtT4 = (unsigned short*)(ws + XTT4_B);
    unsigned short* o1p  = (unsigned short*)(ws + O1P_B);
    float*          ml1  = (float*)(ws + ML1_B);
    unsigned short* a2p  = (unsigned short*)(ws + A2P_B);
    float*          ml2  = (float*)(ws + ML2_B);
    unsigned short* a4p  = (unsigned short*)(ws + A4P_B);
    float*          ml4  = (float*)(ws + ML4_B);
    unsigned short* a2m  = (unsigned short*)(ws + A2M_B);
    unsigned short* a4m  = (unsigned short*)(ws + A4M_B);

    pool_tr<1><<<dim3(64, 4, B_), 256, 0, stream>>>(x, xt1, xtT1);
    pool_tr<2><<<dim3(32, 4, B_), 256, 0, stream>>>(x, xt2, xtT2);
    pool_tr<4><<<dim3(16, 4, B_), 256, 0, stream>>>(x, xt4, xtT4);

    attn_mfma<4096, 2><<<512, 256, 0, stream>>>(xt1, xtT1, o1p, ml1);   // 2 blocks/CU
    attn_mfma<1024, 4><<<256, 256, 0, stream>>>(xt2, xtT2, a2p, ml2);
    attn_mfma<256,  4><<<64,  256, 0, stream>>>(xt4, xtT4, a4p, ml4);

    merge_small<<<2560, 256, 0, stream>>>(a2p, ml2, a4p, ml4, a2m, a4m);
    combine_kernel<<<(B_ * C_ * 64 * 64 + 255) / 256, 256, 0, stream>>>(out, o1p, ml1, a2m, a4m);
}

// Round 6
// 96.346 us; speedup vs baseline: 14.6503x; 1.0924x over previous
//
#include <hip/hip_runtime.h>
#include <hip/hip_bf16.h>
#include <math.h>

typedef __attribute__((ext_vector_type(8))) short bf16x8;
typedef __attribute__((ext_vector_type(4))) float f32x4;

#define B_ 4
#define C_ 128

// ---- workspace byte offsets ----
// Phase A (pools, attn2/4, merge): small-scale buffers live INSIDE o1p's region.
// Phase B (attn1, combine): o1p overwrites them. Total 27,000,832 B.
#define XT1_B   0ull               // bf16 [4][4096][128]           4 MB
#define XTT1_B  4194304ull         // bf16 [4][128][4096]           4 MB
#define OVL_B   8388608ull         // overlap region == o1p
#define XT2_B   (OVL_B + 0ull)          // bf16 [4][1024][128]      1 MB
#define XTT2_B  (OVL_B + 1048576ull)    // bf16 [4][128][1024]      1 MB
#define XT4_B   (OVL_B + 2097152ull)    // bf16 [4][256][128]
#define XTT4_B  (OVL_B + 2359296ull)    // bf16 [4][128][256]
#define A2P_B   (OVL_B + 2621440ull)    // bf16 [4][4][128][1024]   4 MB
#define ML2_B   (OVL_B + 6815744ull)    // f32  [4][4][1024][2]
#define A4P_B   (OVL_B + 6946816ull)    // bf16 [4][4][128][256]    1 MB
#define ML4_B   (OVL_B + 7995392ull)    // f32  [4][4][256][2]
#define O1P_B   8388608ull         // bf16 [4][4][128][4096]       16 MB
#define ML1_B   25165824ull        // f32  [4][4][4096][2]         512 KB
#define A2M_B   25690112ull        // bf16 [4][128][1024]          1 MB
#define A4M_B   26738688ull        // bf16 [4][128][256]           256 KB

#define LOG2E 1.4426950408889634f

// __exp2f collides with a glibc math.h macro on this toolchain; use the
// raw gfx950 builtin (v_exp_f32 computes 2^x).
__device__ __forceinline__ float ex2(float x) { return __builtin_amdgcn_exp2f(x); }

__device__ __forceinline__ unsigned short f2bf(float f) {
    unsigned int u = __builtin_bit_cast(unsigned int, f);
    return (unsigned short)((u + 0x7FFFu + ((u >> 16) & 1u)) >> 16);
}
__device__ __forceinline__ float bf2f(unsigned short u) {
    unsigned int x = ((unsigned int)u) << 16;
    return __builtin_bit_cast(float, x);
}
__device__ __forceinline__ unsigned int pkbf(float lo, float hi) {
    union { __hip_bfloat162 h; unsigned int u; } c;
    c.h = __float22bfloat162_rn(make_float2(lo, hi));   // v_cvt_pk_bf16_f32
    return c.u;
}
__device__ __forceinline__ void gload_lds16(const void* g, void* l) {
    __builtin_amdgcn_global_load_lds(
        (const __attribute__((address_space(1))) unsigned int*)g,
        (__attribute__((address_space(3))) unsigned int*)l, 16, 0, 0);
}

// ---------------- pool + transpose: x[B][C][64][64] -> xt[B][N][C] bf16, xtT[B][C][N] bf16
template<int S>
__global__ __launch_bounds__(256) void pool_tr(const float* __restrict__ x,
                                               unsigned short* __restrict__ xt,
                                               unsigned short* __restrict__ xtT) {
    constexpr int WS = 64 / S;
    constexpr int N  = WS * WS;
    constexpr int RS = S * 64 + 1;
    __shared__ float lds[32 * RS];
    const int hp = blockIdx.x;
    const int c0 = blockIdx.y * 32;
    const int b  = blockIdx.z;
    const int t  = threadIdx.x;

    for (int e = t; e < 32 * S * 64; e += 256) {
        int ci  = e / (S * 64);
        int rem = e - ci * (S * 64);
        lds[ci * RS + rem] =
            x[((size_t)(b * C_ + c0 + ci) * 64 + (hp * S + (rem >> 6))) * 64 + (rem & 63)];
    }
    __syncthreads();

    constexpr float inv = 1.0f / (S * S);
    for (int v = t; v < 32 * WS; v += 256) {
        int ci = v & 31, wp = v >> 5;
        float s = 0.f;
        #pragma unroll
        for (int i = 0; i < S; ++i)
            #pragma unroll
            for (int j = 0; j < S; ++j) s += lds[ci * RS + i * 64 + wp * S + j];
        xt[((size_t)b * N + hp * WS + wp) * C_ + c0 + ci] = f2bf(s * inv);
    }
    for (int v = t; v < 32 * WS; v += 256) {
        int wp = v & (WS - 1), ci = v / WS;
        float s = 0.f;
        #pragma unroll
        for (int i = 0; i < S; ++i)
            #pragma unroll
            for (int j = 0; j < S; ++j) s += lds[ci * RS + i * 64 + wp * S + j];
        xtT[((size_t)(b * C_ + c0 + ci)) * N + hp * WS + wp] = f2bf(s * inv);
    }
}

// ---------------- MFMA flash attention: 4 waves x 32 q-rows, KVBLK=64 dbuf, KV-split.
// exp2-domain softmax (Q pre-scaled by log2e). Writes UNNORMALIZED bf16 partials + (m,l).
// kf/vf LDS fragments are shared across the wave's 2 q-subtiles -> LDS read per work halved.
template<int N, int SPLIT>
__global__ __launch_bounds__(256, 2) void attn_mfma(const unsigned short* __restrict__ xt,
                                                    const unsigned short* __restrict__ xtT,
                                                    unsigned short* __restrict__ op,
                                                    float* __restrict__ ml) {
    __shared__ char lds[65536];          // 2 bufs x (K [64][128]bf16 + V^T [128][64]bf16)
    constexpr int LOG2S = (SPLIT == 2) ? 1 : 2;
    constexpr int QB    = N / 128;                 // q-blocks
    constexpr int W2    = QB * SPLIT / 2;          // work items per XCD
    const int bid   = blockIdx.x;
    const int xcd   = bid & 7;
    const int b     = xcd >> 1;                    // batch pinned to XCD pair (L2 locality)
    const int wi    = (xcd & 1) * W2 + (bid >> 3);
    const int split = wi & (SPLIT - 1);
    const int qx    = wi >> LOG2S;
    const int n0    = qx * 128;
    const int m_beg = split * (N / SPLIT);
    constexpr int NT = N / SPLIT / 64;

    const int tid = threadIdx.x;
    const int w = tid >> 6, lane = tid & 63;
    const int g = lane >> 4, rho = lane & 15;

    const char* xb  = (const char*)(xt  + (size_t)b * N * C_);
    const char* xtb = (const char*)(xtT + (size_t)b * C_ * N);

    // Q fragments (B-operand of S^T mfma), pre-scaled by log2e
    bf16x8 qf[2][4];
    #pragma unroll
    for (int tt = 0; tt < 2; ++tt) {
        const char* qr = xb + (size_t)(n0 + w * 32 + tt * 16 + rho) * 256;
        #pragma unroll
        for (int kc = 0; kc < 4; ++kc) {
            bf16x8 raw = *(const bf16x8*)(qr + kc * 64 + g * 16);
            bf16x8 s;
            #pragma unroll
            for (int e = 0; e < 8; ++e)
                s[e] = (short)f2bf(bf2f((unsigned short)raw[e]) * LOG2E);
            qf[tt][kc] = s;
        }
    }

    auto stage = [&](int buf, int m0) {
        #pragma unroll
        for (int k = 0; k < 4; ++k) {
            int D = (w * 4 + k) * 1024 + lane * 16;
            int row = D >> 8, colb = D & 255;
            gload_lds16(xb + (size_t)(m0 + row) * 256 + (colb ^ ((row & 15) << 4)),
                        lds + buf * 32768 + (w * 4 + k) * 1024);
        }
        #pragma unroll
        for (int k = 0; k < 4; ++k) {
            int D = (w * 4 + k) * 1024 + lane * 16;
            int c = D >> 7, colb = D & 127;
            gload_lds16(xtb + (size_t)c * (2 * N) + m0 * 2 + (colb ^ ((c & 7) << 4)),
                        lds + buf * 32768 + 16384 + (w * 4 + k) * 1024);
        }
    };

    f32x4 acc[2][8];
    #pragma unroll
    for (int tt = 0; tt < 2; ++tt)
        #pragma unroll
        for (int cb = 0; cb < 8; ++cb) acc[tt][cb] = (f32x4){0.f, 0.f, 0.f, 0.f};
    float m_run[2] = {-INFINITY, -INFINITY};
    float l_lane[2] = {0.f, 0.f};

    stage(0, m_beg);
    asm volatile("s_waitcnt vmcnt(0)" ::: "memory");
    __syncthreads();

    for (int t = 0; t < NT; ++t) {
        const int cur = t & 1;
        if (t + 1 < NT) stage(cur ^ 1, m_beg + (t + 1) * 64);
        __builtin_amdgcn_sched_barrier(0);

        const char* kbuf = lds + cur * 32768;
        const char* vbuf = kbuf + 16384;

        // ---- QK^T (S^T): A = K rows (permuted m-tiles), B = Q; kf shared across tt
        f32x4 accS[2][4];
        #pragma unroll
        for (int tt = 0; tt < 2; ++tt)
            #pragma unroll
            for (int mb = 0; mb < 4; ++mb) accS[tt][mb] = (f32x4){0.f, 0.f, 0.f, 0.f};
        #pragma unroll
        for (int mb = 0; mb < 4; ++mb) {
            const int rowm = ((mb >> 1) << 5) + ((mb & 1) << 2) + ((rho >> 2) << 3) + (rho & 3);
            const char* kb = kbuf + rowm * 256;
            const int swz = (rowm & 15) << 4;
            #pragma unroll
            for (int kc = 0; kc < 4; ++kc) {
                bf16x8 kf = *(const bf16x8*)(kb + ((kc * 64 + g * 16) ^ swz));
                accS[0][mb] = __builtin_amdgcn_mfma_f32_16x16x32_bf16(kf, qf[0][kc], accS[0][mb], 0, 0, 0);
                accS[1][mb] = __builtin_amdgcn_mfma_f32_16x16x32_bf16(kf, qf[1][kc], accS[1][mb], 0, 0, 0);
            }
        }

        // ---- online softmax in exp2 domain, defer-max (tau=6), deferred l-reduce
        bf16x8 pb[2][2];
        #pragma unroll
        for (int tt = 0; tt < 2; ++tt) {
            float tm = accS[tt][0][0];
            #pragma unroll
            for (int mb = 0; mb < 4; ++mb)
                #pragma unroll
                for (int r = 0; r < 4; ++r) tm = fmaxf(tm, accS[tt][mb][r]);
            tm = fmaxf(tm, __shfl_xor(tm, 16));
            tm = fmaxf(tm, __shfl_xor(tm, 32));
            if (!__all(tm <= m_run[tt] + 6.0f)) {
                float nm = fmaxf(m_run[tt], tm);
                float sc = ex2(m_run[tt] - nm);
                l_lane[tt] *= sc;
                m_run[tt] = nm;
                #pragma unroll
                for (int cb = 0; cb < 8; ++cb) {
                    acc[tt][cb][0] *= sc; acc[tt][cb][1] *= sc;
                    acc[tt][cb][2] *= sc; acc[tt][cb][3] *= sc;
                }
            }
            float p[4][4];
            #pragma unroll
            for (int mb = 0; mb < 4; ++mb)
                #pragma unroll
                for (int r = 0; r < 4; ++r) {
                    p[mb][r] = ex2(accS[tt][mb][r] - m_run[tt]);
                    l_lane[tt] += p[mb][r];
                }
            #pragma unroll
            for (int ks = 0; ks < 2; ++ks) {
                union { bf16x8 v; unsigned int u[4]; } pk;
                pk.u[0] = pkbf(p[2 * ks][0],     p[2 * ks][1]);
                pk.u[1] = pkbf(p[2 * ks][2],     p[2 * ks][3]);
                pk.u[2] = pkbf(p[2 * ks + 1][0], p[2 * ks + 1][1]);
                pk.u[3] = pkbf(p[2 * ks + 1][2], p[2 * ks + 1][3]);
                pb[tt][ks] = pk.v;
            }
        }

        // ---- PV: A = V^T rows (c), B = P^T (regs); vf shared across tt
        #pragma unroll
        for (int cb = 0; cb < 8; ++cb) {
            const int c = cb * 16 + rho;
            const char* vb = vbuf + c * 128;
            const int vswz = (c & 7) << 4;
            #pragma unroll
            for (int ks = 0; ks < 2; ++ks) {
                bf16x8 vf = *(const bf16x8*)(vb + ((ks * 64 + g * 16) ^ vswz));
                acc[0][cb] = __builtin_amdgcn_mfma_f32_16x16x32_bf16(vf, pb[0][ks], acc[0][cb], 0, 0, 0);
                acc[1][cb] = __builtin_amdgcn_mfma_f32_16x16x32_bf16(vf, pb[1][ks], acc[1][cb], 0, 0, 0);
            }
        }

        if (t + 1 < NT) {
            asm volatile("s_waitcnt vmcnt(0)" ::: "memory");
            __syncthreads();
        }
    }

    // epilogue: reduce l across g-lanes, store unnormalized partials + (m,l)
    #pragma unroll
    for (int tt = 0; tt < 2; ++tt) {
        l_lane[tt] += __shfl_xor(l_lane[tt], 16);
        l_lane[tt] += __shfl_xor(l_lane[tt], 32);
        const int n = n0 + w * 32 + tt * 16 + rho;
        #pragma unroll
        for (int cb = 0; cb < 8; ++cb)
            #pragma unroll
            for (int r = 0; r < 4; ++r)
                op[((size_t)(split * B_ + b) * C_ + cb * 16 + g * 4 + r) * N + n] = f2bf(acc[tt][cb][r]);
        if (g == 0) {
            ml[((size_t)(split * B_ + b) * N + n) * 2 + 0] = m_run[tt];
            ml[((size_t)(split * B_ + b) * N + n) * 2 + 1] = l_lane[tt];
        }
    }
}

// ---------------- merge 4-way partials for scales 2 and 4 (exp2 domain)
__global__ __launch_bounds__(256) void merge_small(const unsigned short* __restrict__ a2p,
                                                   const float* __restrict__ ml2,
                                                   const unsigned short* __restrict__ a4p,
                                                   const float* __restrict__ ml4,
                                                   unsigned short* __restrict__ a2m,
                                                   unsigned short* __restrict__ a4m) {
    int idx = blockIdx.x * 256 + threadIdx.x;
    if (idx < 4 * 128 * 1024) {
        int n = idx & 1023, c = (idx >> 10) & 127, b = idx >> 17;
        float M = -INFINITY;
        #pragma unroll
        for (int s = 0; s < 4; ++s) M = fmaxf(M, ml2[((s * 4 + b) * 1024 + n) * 2]);
        float L = 0.f, O = 0.f;
        #pragma unroll
        for (int s = 0; s < 4; ++s) {
            float wgt = ex2(ml2[((s * 4 + b) * 1024 + n) * 2] - M);
            L += ml2[((s * 4 + b) * 1024 + n) * 2 + 1] * wgt;
            O += bf2f(a2p[((size_t)((s * 4 + b) * 128 + c)) * 1024 + n]) * wgt;
        }
        a2m[((size_t)(b * 128 + c)) * 1024 + n] = f2bf(O / L);
    } else {
        int i2 = idx - 4 * 128 * 1024;
        if (i2 < 4 * 128 * 256) {
            int n = i2 & 255, c = (i2 >> 8) & 127, b = i2 >> 15;
            float M = -INFINITY;
            #pragma unroll
            for (int s = 0; s < 4; ++s) M = fmaxf(M, ml4[((s * 4 + b) * 256 + n) * 2]);
            float L = 0.f, O = 0.f;
            #pragma unroll
            for (int s = 0; s < 4; ++s) {
                float wgt = ex2(ml4[((s * 4 + b) * 256 + n) * 2] - M);
                L += ml4[((s * 4 + b) * 256 + n) * 2 + 1] * wgt;
                O += bf2f(a4p[((size_t)((s * 4 + b) * 128 + c)) * 256 + n]) * wgt;
            }
            a4m[((size_t)(b * 128 + c)) * 256 + n] = f2bf(O / L);
        }
    }
}

// ---------------- bilinear upsample (half-pixel centers, clamp) from bf16 grid
template<int HS>
__device__ __forceinline__ float bilin(const unsigned short* __restrict__ a, int h, int w) {
    constexpr float sc = (float)HS / 64.0f;
    float sh = (h + 0.5f) * sc - 0.5f;
    float sw = (w + 0.5f) * sc - 0.5f;
    int h0 = (int)floorf(sh); float fh = sh - (float)h0;
    int w0 = (int)floorf(sw); float fw = sw - (float)w0;
    int h0c = max(h0, 0), h1c = min(h0 + 1, HS - 1);
    int w0c = max(w0, 0), w1c = min(w0 + 1, HS - 1);
    float v00 = bf2f(a[h0c * HS + w0c]), v01 = bf2f(a[h0c * HS + w1c]);
    float v10 = bf2f(a[h1c * HS + w0c]), v11 = bf2f(a[h1c * HS + w1c]);
    return (1.f - fh) * ((1.f - fw) * v00 + fw * v01)
         +        fh  * ((1.f - fw) * v10 + fw * v11);
}

// ---------------- scale-1 4-way merge + upsampled adds (exp2 domain)
__global__ __launch_bounds__(256) void combine_kernel(float* __restrict__ out,
                                                      const unsigned short* __restrict__ o1p,
                                                      const float* __restrict__ ml1,
                                                      const unsigned short* __restrict__ a2m,
                                                      const unsigned short* __restrict__ a4m) {
    int e = blockIdx.x * 256 + threadIdx.x;
    if (e >= B_ * C_ * 64 * 64) return;
    int w  = e & 63;
    int h  = (e >> 6) & 63;
    int bc = e >> 12;
    int b  = bc >> 7;
    int n  = (h << 6) | w;
    float M = -INFINITY;
    #pragma unroll
    for (int s = 0; s < 4; ++s) M = fmaxf(M, ml1[((size_t)(s * 4 + b) * 4096 + n) * 2]);
    float num = 0.f, den = 0.f;
    #pragma unroll
    for (int s = 0; s < 4; ++s) {
        float wgt = ex2(ml1[((size_t)(s * 4 + b) * 4096 + n) * 2] - M);
        den += ml1[((size_t)(s * 4 + b) * 4096 + n) * 2 + 1] * wgt;
        num += bf2f(o1p[((size_t)(s * 512 + bc)) * 4096 + n]) * wgt;
    }
    float v = num / den;
    v += bilin<32>(a2m + (size_t)bc * 1024, h, w);
    v += bilin<16>(a4m + (size_t)bc * 256,  h, w);
    out[e] = v;
}

extern "C" void kernel_launch(void* const* d_in, const int* in_sizes, int n_in,
                              void* d_out, int out_size, void* d_ws, size_t ws_size,
                              hipStream_t stream) {
    const float* x = (const float*)d_in[0];
    float* out = (float*)d_out;
    char* ws = (char*)d_ws;
    unsigned short* xt1  = (unsigned short*)(ws + XT1_B);
    unsigned short* xtT1 = (unsigned short*)(ws + XTT1_B);
    unsigned short* xt2  = (unsigned short*)(ws + XT2_B);
    unsigned short* xtT2 = (unsigned short*)(ws + XTT2_B);
    unsigned short* xt4  = (unsigned short*)(ws + XT4_B);
    unsigned short* xtT4 = (unsigned short*)(ws + XTT4_B);
    unsigned short* a2p  = (unsigned short*)(ws + A2P_B);
    float*          ml2  = (float*)(ws + ML2_B);
    unsigned short* a4p  = (unsigned short*)(ws + A4P_B);
    float*          ml4  = (float*)(ws + ML4_B);
    unsigned short* o1p  = (unsigned short*)(ws + O1P_B);
    float*          ml1  = (float*)(ws + ML1_B);
    unsigned short* a2m  = (unsigned short*)(ws + A2M_B);
    unsigned short* a4m  = (unsigned short*)(ws + A4M_B);

    // Phase A: pools + small scales + their merge (uses the o1p-overlap region)
    pool_tr<1><<<dim3(64, 4, B_), 256, 0, stream>>>(x, xt1, xtT1);
    pool_tr<2><<<dim3(32, 4, B_), 256, 0, stream>>>(x, xt2, xtT2);
    pool_tr<4><<<dim3(16, 4, B_), 256, 0, stream>>>(x, xt4, xtT4);
    attn_mfma<1024, 4><<<128, 256, 0, stream>>>(xt2, xtT2, a2p, ml2);
    attn_mfma<256,  4><<<32,  256, 0, stream>>>(xt4, xtT4, a4p, ml4);
    merge_small<<<2560, 256, 0, stream>>>(a2p, ml2, a4p, ml4, a2m, a4m);

    // Phase B: scale-1 (o1p overwrites the overlap region) + final combine
    attn_mfma<4096, 4><<<512, 256, 0, stream>>>(xt1, xtT1, o1p, ml1);
    combine_kernel<<<(B_ * C_ * 64 * 64 + 255) / 256, 256, 0, stream>>>(out, o1p, ml1, a2m, a4m);
}

// Round 7
// 93.404 us; speedup vs baseline: 15.1117x; 1.0315x over previous
//
#include <hip/hip_runtime.h>
#include <hip/hip_bf16.h>
#include <math.h>

typedef __attribute__((ext_vector_type(8))) short bf16x8;
typedef __attribute__((ext_vector_type(4))) float f32x4;

#define B_ 4
#define C_ 128

// ---- workspace byte offsets ----
// Phase A (pool, attn2/4, merge) uses the o1p-overlap region; Phase B (attn1, combine)
// overwrites it. Total 27,000,832 B (same as round 6).
#define XT1_B   0ull               // bf16 [4][4096][128]           4 MB
#define XTT1_B  4194304ull         // bf16 [4][128][4096]           4 MB
#define OVL_B   8388608ull         // overlap region == o1p (16 MB)
#define XT2_B   (OVL_B + 0ull)           // bf16 [4][1024][128]     1 MB
#define XTT2_B  (OVL_B + 1048576ull)     // bf16 [4][128][1024]     1 MB
#define XT4_B   (OVL_B + 2097152ull)     // bf16 [4][256][128]
#define XTT4_B  (OVL_B + 2359296ull)     // bf16 [4][128][256]
#define A2P_B   (OVL_B + 2621440ull)     // bf16 [8][4][128][1024]  8 MB
#define ML2_B   (OVL_B + 11010048ull)    // f32  [8][4][1024][2]    256 KB
#define A4P_B   (OVL_B + 11272192ull)    // bf16 [2][4][128][256]   512 KB
#define ML4_B   (OVL_B + 11796480ull)    // f32  [2][4][256][2]     16 KB
#define O1P_B   8388608ull         // bf16 [4][4][128][4096]       16 MB
#define ML1_B   25165824ull        // f32  [4][4][4096][2]         512 KB
#define A2M_B   25690112ull        // bf16 [4][128][1024]          1 MB
#define A4M_B   26738688ull        // bf16 [4][128][256]           256 KB

#define LOG2E 1.4426950408889634f

// __exp2f collides with a glibc math.h macro on this toolchain; raw builtin = v_exp_f32 (2^x).
__device__ __forceinline__ float ex2(float x) { return __builtin_amdgcn_exp2f(x); }

__device__ __forceinline__ unsigned short f2bf(float f) {
    unsigned int u = __builtin_bit_cast(unsigned int, f);
    return (unsigned short)((u + 0x7FFFu + ((u >> 16) & 1u)) >> 16);
}
__device__ __forceinline__ float bf2f(unsigned short u) {
    unsigned int x = ((unsigned int)u) << 16;
    return __builtin_bit_cast(float, x);
}
__device__ __forceinline__ unsigned int pkbf(float lo, float hi) {
    union { __hip_bfloat162 h; unsigned int u; } c;
    c.h = __float22bfloat162_rn(make_float2(lo, hi));   // v_cvt_pk_bf16_f32
    return c.u;
}
__device__ __forceinline__ void gload_lds16(const void* g, void* l) {
    __builtin_amdgcn_global_load_lds(
        (const __attribute__((address_space(1))) unsigned int*)g,
        (__attribute__((address_space(3))) unsigned int*)l, 16, 0, 0);
}

// ---------------- fused pool: x[B][C][64][64] -> {xt,xtT} for scales 1,2,4 (reads x once)
__global__ __launch_bounds__(256) void pool_all(const float* __restrict__ x,
                                                unsigned short* __restrict__ xt1,
                                                unsigned short* __restrict__ xtT1,
                                                unsigned short* __restrict__ xt2,
                                                unsigned short* __restrict__ xtT2,
                                                unsigned short* __restrict__ xt4,
                                                unsigned short* __restrict__ xtT4) {
    constexpr int RS = 257;                 // 4 rows x 64 cols payload + 1 pad
    __shared__ float lds[32 * RS];
    const int hp4 = blockIdx.x;             // group of 4 image rows
    const int c0  = blockIdx.y * 32;
    const int b   = blockIdx.z;
    const int t   = threadIdx.x;

    #pragma unroll
    for (int i = 0; i < 8; ++i) {           // 8192 floats, float4-coalesced
        int e4 = (i * 256 + t) * 4;
        int ci = e4 >> 8, rem = e4 & 255;
        float4 v = *reinterpret_cast<const float4*>(
            &x[((size_t)(b * C_ + c0 + ci) * 64 + (hp4 * 4 + (rem >> 6))) * 64 + (rem & 63)]);
        *reinterpret_cast<float4*>(&lds[ci * RS + rem]) = v;
    }
    __syncthreads();

    // scale 1
    #pragma unroll
    for (int i = 0; i < 32; ++i) {
        int v = i * 256 + t;
        int ci = v & 31, pos = v >> 5;
        xt1[((size_t)b * 4096 + hp4 * 256 + pos) * C_ + c0 + ci] = f2bf(lds[ci * RS + pos]);
    }
    #pragma unroll
    for (int i = 0; i < 32; ++i) {
        int ci = i, pos = t;
        xtT1[((size_t)(b * C_ + c0 + ci)) * 4096 + hp4 * 256 + pos] = f2bf(lds[ci * RS + pos]);
    }
    // scale 2
    #pragma unroll
    for (int i = 0; i < 8; ++i) {
        int v = i * 256 + t;
        int ci = v & 31, pz = v >> 5;
        int r2 = pz >> 5, w2 = pz & 31;
        float s = lds[ci * RS + (2*r2)*64 + 2*w2]     + lds[ci * RS + (2*r2)*64 + 2*w2 + 1]
                + lds[ci * RS + (2*r2+1)*64 + 2*w2]   + lds[ci * RS + (2*r2+1)*64 + 2*w2 + 1];
        xt2[((size_t)b * 1024 + (hp4*2 + r2)*32 + w2) * C_ + c0 + ci] = f2bf(s * 0.25f);
    }
    #pragma unroll
    for (int i = 0; i < 8; ++i) {
        int v = i * 256 + t;
        int pz = v & 63, ci = v >> 6;
        int r2 = pz >> 5, w2 = pz & 31;
        float s = lds[ci * RS + (2*r2)*64 + 2*w2]     + lds[ci * RS + (2*r2)*64 + 2*w2 + 1]
                + lds[ci * RS + (2*r2+1)*64 + 2*w2]   + lds[ci * RS + (2*r2+1)*64 + 2*w2 + 1];
        xtT2[((size_t)(b * C_ + c0 + ci)) * 1024 + (hp4*2 + r2)*32 + w2] = f2bf(s * 0.25f);
    }
    // scale 4
    #pragma unroll
    for (int i = 0; i < 2; ++i) {
        int v = i * 256 + t;
        int ci = v & 31, w4 = v >> 5;
        float s = 0.f;
        #pragma unroll
        for (int r = 0; r < 4; ++r)
            #pragma unroll
            for (int j = 0; j < 4; ++j) s += lds[ci * RS + r*64 + w4*4 + j];
        xt4[((size_t)b * 256 + hp4*16 + w4) * C_ + c0 + ci] = f2bf(s * 0.0625f);
    }
    #pragma unroll
    for (int i = 0; i < 2; ++i) {
        int v = i * 256 + t;
        int w4 = v & 15, ci = v >> 4;
        float s = 0.f;
        #pragma unroll
        for (int r = 0; r < 4; ++r)
            #pragma unroll
            for (int j = 0; j < 4; ++j) s += lds[ci * RS + r*64 + w4*4 + j];
        xtT4[((size_t)(b * C_ + c0 + ci)) * 256 + hp4*16 + w4] = f2bf(s * 0.0625f);
    }
}

// ---------------- MFMA flash attention: 4 waves x 32 q-rows, KVBLK=64 dbuf, KV-split.
// All LDS/staging addresses strength-reduced to per-lane constants; 2-tile-unrolled loop
// makes the LDS buffer base compile-time constant.
template<int N, int SPLIT>
__global__ __launch_bounds__(256, 2) void attn_mfma(const unsigned short* __restrict__ xt,
                                                    const unsigned short* __restrict__ xtT,
                                                    unsigned short* __restrict__ op,
                                                    float* __restrict__ ml) {
    __shared__ char lds[65536];
    constexpr int LOG2S = (SPLIT == 2) ? 1 : ((SPLIT == 4) ? 2 : 3);
    constexpr int QB = N / 128;
    constexpr int W2 = QB * SPLIT / 2;
    constexpr int NT = N / SPLIT / 64;
    static_assert(NT % 2 == 0, "even NT required");
    const int bid   = blockIdx.x;
    const int xcd   = bid & 7;
    const int b     = xcd >> 1;                 // batch pinned to XCD pair (L2 locality)
    const int wi    = (xcd & 1) * W2 + (bid >> 3);
    const int split = wi & (SPLIT - 1);
    const int qx    = wi >> LOG2S;
    const int n0    = qx * 128;
    const int m_beg = split * (N / SPLIT);

    const int tid = threadIdx.x;
    const int w = tid >> 6, lane = tid & 63;
    const int g = lane >> 4, rho = lane & 15;

    const char* xb  = (const char*)(xt  + (size_t)b * N * C_);
    const char* xtb = (const char*)(xtT + (size_t)b * C_ * N);

    // Q fragments (B-operand of S^T mfma), pre-scaled by log2e
    bf16x8 qf[2][4];
    #pragma unroll
    for (int tt = 0; tt < 2; ++tt) {
        const char* qr = xb + (size_t)(n0 + w * 32 + tt * 16 + rho) * 256;
        #pragma unroll
        for (int kc = 0; kc < 4; ++kc) {
            bf16x8 raw = *(const bf16x8*)(qr + kc * 64 + g * 16);
            bf16x8 s;
            #pragma unroll
            for (int e = 0; e < 8; ++e)
                s[e] = (short)f2bf(bf2f((unsigned short)raw[e]) * LOG2E);
            qf[tt][kc] = s;
        }
    }

    // ---- per-lane constant offsets (computed once) ----
    int kOff[4], vOff[4];
    #pragma unroll
    for (int k = 0; k < 4; ++k) {
        int D = (w * 4 + k) * 1024 + lane * 16;
        int row = D >> 8, colb = D & 255;
        kOff[k] = row * 256 + (colb ^ ((row & 15) << 4));
        int c = D >> 7, cb2 = D & 127;
        vOff[k] = c * (2 * N) + (cb2 ^ ((c & 7) << 4));
    }
    int qkOff[4][4], pvOff[8][2];
    #pragma unroll
    for (int mb = 0; mb < 4; ++mb) {
        int rowm = ((mb >> 1) << 5) + ((mb & 1) << 2) + ((rho >> 2) << 3) + (rho & 3);
        int swz = (rowm & 15) << 4;
        #pragma unroll
        for (int kc = 0; kc < 4; ++kc)
            qkOff[mb][kc] = rowm * 256 + ((kc * 64 + g * 16) ^ swz);
    }
    #pragma unroll
    for (int cb = 0; cb < 8; ++cb) {
        int c = cb * 16 + rho;
        int vswz = (c & 7) << 4;
        #pragma unroll
        for (int ks = 0; ks < 2; ++ks)
            pvOff[cb][ks] = 16384 + c * 128 + ((ks * 64 + g * 16) ^ vswz);
    }
    const char* kSrc = xb  + (size_t)m_beg * 256;
    const char* vSrc = xtb + (size_t)m_beg * 2;

    auto stage = [&](char* ldsb) {
        #pragma unroll
        for (int k = 0; k < 4; ++k)
            gload_lds16(kSrc + kOff[k], ldsb + (w * 4 + k) * 1024);
        #pragma unroll
        for (int k = 0; k < 4; ++k)
            gload_lds16(vSrc + vOff[k], ldsb + 16384 + (w * 4 + k) * 1024);
        kSrc += 64 * 256;     // next KV tile
        vSrc += 64 * 2;
    };

    f32x4 acc[2][8];
    #pragma unroll
    for (int tt = 0; tt < 2; ++tt)
        #pragma unroll
        for (int cb = 0; cb < 8; ++cb) acc[tt][cb] = (f32x4){0.f, 0.f, 0.f, 0.f};
    float m_run[2] = {-INFINITY, -INFINITY};
    float l_lane[2] = {0.f, 0.f};

    auto compute = [&](const char* base) {
        // ---- QK^T (S^T): A = K rows (permuted m-tiles), B = Q; kf shared across tt
        f32x4 accS[2][4];
        #pragma unroll
        for (int tt = 0; tt < 2; ++tt)
            #pragma unroll
            for (int mb = 0; mb < 4; ++mb) accS[tt][mb] = (f32x4){0.f, 0.f, 0.f, 0.f};
        __builtin_amdgcn_s_setprio(1);
        #pragma unroll
        for (int mb = 0; mb < 4; ++mb)
            #pragma unroll
            for (int kc = 0; kc < 4; ++kc) {
                bf16x8 kf = *(const bf16x8*)(base + qkOff[mb][kc]);
                accS[0][mb] = __builtin_amdgcn_mfma_f32_16x16x32_bf16(kf, qf[0][kc], accS[0][mb], 0, 0, 0);
                accS[1][mb] = __builtin_amdgcn_mfma_f32_16x16x32_bf16(kf, qf[1][kc], accS[1][mb], 0, 0, 0);
            }
        __builtin_amdgcn_s_setprio(0);

        // ---- online softmax in exp2 domain, defer-max (tau=6), deferred l-reduce
        bf16x8 pb[2][2];
        #pragma unroll
        for (int tt = 0; tt < 2; ++tt) {
            float tm = accS[tt][0][0];
            #pragma unroll
            for (int mb = 0; mb < 4; ++mb)
                #pragma unroll
                for (int r = 0; r < 4; ++r) tm = fmaxf(tm, accS[tt][mb][r]);
            tm = fmaxf(tm, __shfl_xor(tm, 16));
            tm = fmaxf(tm, __shfl_xor(tm, 32));
            if (!__all(tm <= m_run[tt] + 6.0f)) {
                float nm = fmaxf(m_run[tt], tm);
                float sc = ex2(m_run[tt] - nm);
                l_lane[tt] *= sc;
                m_run[tt] = nm;
                #pragma unroll
                for (int cb = 0; cb < 8; ++cb) {
                    acc[tt][cb][0] *= sc; acc[tt][cb][1] *= sc;
                    acc[tt][cb][2] *= sc; acc[tt][cb][3] *= sc;
                }
            }
            float p[4][4];
            #pragma unroll
            for (int mb = 0; mb < 4; ++mb)
                #pragma unroll
                for (int r = 0; r < 4; ++r) {
                    p[mb][r] = ex2(accS[tt][mb][r] - m_run[tt]);
                    l_lane[tt] += p[mb][r];
                }
            #pragma unroll
            for (int ks = 0; ks < 2; ++ks) {
                union { bf16x8 v; unsigned int u[4]; } pk;
                pk.u[0] = pkbf(p[2 * ks][0],     p[2 * ks][1]);
                pk.u[1] = pkbf(p[2 * ks][2],     p[2 * ks][3]);
                pk.u[2] = pkbf(p[2 * ks + 1][0], p[2 * ks + 1][1]);
                pk.u[3] = pkbf(p[2 * ks + 1][2], p[2 * ks + 1][3]);
                pb[tt][ks] = pk.v;
            }
        }

        // ---- PV: A = V^T rows (c), B = P^T (regs); vf shared across tt
        __builtin_amdgcn_s_setprio(1);
        #pragma unroll
        for (int cb = 0; cb < 8; ++cb)
            #pragma unroll
            for (int ks = 0; ks < 2; ++ks) {
                bf16x8 vf = *(const bf16x8*)(base + pvOff[cb][ks]);
                acc[0][cb] = __builtin_amdgcn_mfma_f32_16x16x32_bf16(vf, pb[0][ks], acc[0][cb], 0, 0, 0);
                acc[1][cb] = __builtin_amdgcn_mfma_f32_16x16x32_bf16(vf, pb[1][ks], acc[1][cb], 0, 0, 0);
            }
        __builtin_amdgcn_s_setprio(0);
    };

    stage(lds);
    asm volatile("s_waitcnt vmcnt(0)" ::: "memory");
    __syncthreads();

    #pragma unroll 1
    for (int t = 0; t < NT; t += 2) {
        stage(lds + 32768);                       // tile t+1 (always exists: NT even)
        __builtin_amdgcn_sched_barrier(0);
        compute(lds);
        asm volatile("s_waitcnt vmcnt(0)" ::: "memory");
        __syncthreads();
        if (t + 2 < NT) stage(lds);               // tile t+2
        __builtin_amdgcn_sched_barrier(0);
        compute(lds + 32768);
        if (t + 2 < NT) {
            asm volatile("s_waitcnt vmcnt(0)" ::: "memory");
            __syncthreads();
        }
    }

    // epilogue: reduce l across g-lanes, store unnormalized partials + (m,l)
    #pragma unroll
    for (int tt = 0; tt < 2; ++tt) {
        l_lane[tt] += __shfl_xor(l_lane[tt], 16);
        l_lane[tt] += __shfl_xor(l_lane[tt], 32);
        const int n = n0 + w * 32 + tt * 16 + rho;
        #pragma unroll
        for (int cb = 0; cb < 8; ++cb)
            #pragma unroll
            for (int r = 0; r < 4; ++r)
                op[((size_t)(split * B_ + b) * C_ + cb * 16 + g * 4 + r) * N + n] = f2bf(acc[tt][cb][r]);
        if (g == 0) {
            ml[((size_t)(split * B_ + b) * N + n) * 2 + 0] = m_run[tt];
            ml[((size_t)(split * B_ + b) * N + n) * 2 + 1] = l_lane[tt];
        }
    }
}

// ---------------- merge partials: scale-2 (8-way) and scale-4 (2-way), exp2 domain
__global__ __launch_bounds__(256) void merge_small(const unsigned short* __restrict__ a2p,
                                                   const float* __restrict__ ml2,
                                                   const unsigned short* __restrict__ a4p,
                                                   const float* __restrict__ ml4,
                                                   unsigned short* __restrict__ a2m,
                                                   unsigned short* __restrict__ a4m) {
    int idx = blockIdx.x * 256 + threadIdx.x;
    if (idx < 4 * 128 * 1024) {
        int n = idx & 1023, c = (idx >> 10) & 127, b = idx >> 17;
        float M = -INFINITY;
        #pragma unroll
        for (int s = 0; s < 8; ++s) M = fmaxf(M, ml2[((s * 4 + b) * 1024 + n) * 2]);
        float L = 0.f, O = 0.f;
        #pragma unroll
        for (int s = 0; s < 8; ++s) {
            float wgt = ex2(ml2[((s * 4 + b) * 1024 + n) * 2] - M);
            L += ml2[((s * 4 + b) * 1024 + n) * 2 + 1] * wgt;
            O += bf2f(a2p[((size_t)((s * 4 + b) * 128 + c)) * 1024 + n]) * wgt;
        }
        a2m[((size_t)(b * 128 + c)) * 1024 + n] = f2bf(O / L);
    } else {
        int i2 = idx - 4 * 128 * 1024;
        if (i2 < 4 * 128 * 256) {
            int n = i2 & 255, c = (i2 >> 8) & 127, b = i2 >> 15;
            float M = fmaxf(ml4[((0 * 4 + b) * 256 + n) * 2], ml4[((1 * 4 + b) * 256 + n) * 2]);
            float L = 0.f, O = 0.f;
            #pragma unroll
            for (int s = 0; s < 2; ++s) {
                float wgt = ex2(ml4[((s * 4 + b) * 256 + n) * 2] - M);
                L += ml4[((s * 4 + b) * 256 + n) * 2 + 1] * wgt;
                O += bf2f(a4p[((size_t)((s * 4 + b) * 128 + c)) * 256 + n]) * wgt;
            }
            a4m[((size_t)(b * 128 + c)) * 256 + n] = f2bf(O / L);
        }
    }
}

// ---------------- bilinear upsample (half-pixel centers, clamp) from bf16 grid
template<int HS>
__device__ __forceinline__ float bilin(const unsigned short* __restrict__ a, int h, int w) {
    constexpr float sc = (float)HS / 64.0f;
    float sh = (h + 0.5f) * sc - 0.5f;
    float sw = (w + 0.5f) * sc - 0.5f;
    int h0 = (int)floorf(sh); float fh = sh - (float)h0;
    int w0 = (int)floorf(sw); float fw = sw - (float)w0;
    int h0c = max(h0, 0), h1c = min(h0 + 1, HS - 1);
    int w0c = max(w0, 0), w1c = min(w0 + 1, HS - 1);
    float v00 = bf2f(a[h0c * HS + w0c]), v01 = bf2f(a[h0c * HS + w1c]);
    float v10 = bf2f(a[h1c * HS + w0c]), v11 = bf2f(a[h1c * HS + w1c]);
    return (1.f - fh) * ((1.f - fw) * v00 + fw * v01)
         +        fh  * ((1.f - fw) * v10 + fw * v11);
}

// ---------------- scale-1 4-way merge + upsampled adds (exp2 domain)
__global__ __launch_bounds__(256) void combine_kernel(float* __restrict__ out,
                                                      const unsigned short* __restrict__ o1p,
                                                      const float* __restrict__ ml1,
                                                      const unsigned short* __restrict__ a2m,
                                                      const unsigned short* __restrict__ a4m) {
    int e = blockIdx.x * 256 + threadIdx.x;
    if (e >= B_ * C_ * 64 * 64) return;
    int w  = e & 63;
    int h  = (e >> 6) & 63;
    int bc = e >> 12;
    int b  = bc >> 7;
    int n  = (h << 6) | w;
    float M = -INFINITY;
    #pragma unroll
    for (int s = 0; s < 4; ++s) M = fmaxf(M, ml1[((size_t)(s * 4 + b) * 4096 + n) * 2]);
    float num = 0.f, den = 0.f;
    #pragma unroll
    for (int s = 0; s < 4; ++s) {
        float wgt = ex2(ml1[((size_t)(s * 4 + b) * 4096 + n) * 2] - M);
        den += ml1[((size_t)(s * 4 + b) * 4096 + n) * 2 + 1] * wgt;
        num += bf2f(o1p[((size_t)(s * 512 + bc)) * 4096 + n]) * wgt;
    }
    float v = num / den;
    v += bilin<32>(a2m + (size_t)bc * 1024, h, w);
    v += bilin<16>(a4m + (size_t)bc * 256,  h, w);
    out[e] = v;
}

extern "C" void kernel_launch(void* const* d_in, const int* in_sizes, int n_in,
                              void* d_out, int out_size, void* d_ws, size_t ws_size,
                              hipStream_t stream) {
    const float* x = (const float*)d_in[0];
    float* out = (float*)d_out;
    char* ws = (char*)d_ws;
    unsigned short* xt1  = (unsigned short*)(ws + XT1_B);
    unsigned short* xtT1 = (unsigned short*)(ws + XTT1_B);
    unsigned short* xt2  = (unsigned short*)(ws + XT2_B);
    unsigned short* xtT2 = (unsigned short*)(ws + XTT2_B);
    unsigned short* xt4  = (unsigned short*)(ws + XT4_B);
    unsigned short* xtT4 = (unsigned short*)(ws + XTT4_B);
    unsigned short* a2p  = (unsigned short*)(ws + A2P_B);
    float*          ml2  = (float*)(ws + ML2_B);
    unsigned short* a4p  = (unsigned short*)(ws + A4P_B);
    float*          ml4  = (float*)(ws + ML4_B);
    unsigned short* o1p  = (unsigned short*)(ws + O1P_B);
    float*          ml1  = (float*)(ws + ML1_B);
    unsigned short* a2m  = (unsigned short*)(ws + A2M_B);
    unsigned short* a4m  = (unsigned short*)(ws + A4M_B);

    // Phase A: fused pool + small scales + their merge (uses the o1p-overlap region)
    pool_all<<<dim3(16, 4, B_), 256, 0, stream>>>(x, xt1, xtT1, xt2, xtT2, xt4, xtT4);
    attn_mfma<1024, 8><<<256, 256, 0, stream>>>(xt2, xtT2, a2p, ml2);
    attn_mfma<256,  2><<<16,  256, 0, stream>>>(xt4, xtT4, a4p, ml4);
    merge_small<<<2560, 256, 0, stream>>>(a2p, ml2, a4p, ml4, a2m, a4m);

    // Phase B: scale-1 (o1p overwrites the overlap region) + final combine
    attn_mfma<4096, 4><<<512, 256, 0, stream>>>(xt1, xtT1, o1p, ml1);
    combine_kernel<<<(B_ * C_ * 64 * 64 + 255) / 256, 256, 0, stream>>>(out, o1p, ml1, a2m, a4m);
}

// Round 8
// 88.720 us; speedup vs baseline: 15.9095x; 1.0528x over previous
//
#include <hip/hip_runtime.h>
#include <hip/hip_bf16.h>
#include <math.h>

typedef __attribute__((ext_vector_type(8))) short bf16x8;
typedef __attribute__((ext_vector_type(4))) float f32x4;

#define B_ 4
#define C_ 128

// ---- workspace byte offsets ----
#define XT1_B   0ull               // bf16 [4][4096][128]           4 MB
#define XTT1_B  4194304ull         // bf16 [4][128][4096]           4 MB
#define OVL_B   8388608ull         // overlap region == o1p (16 MB)
#define XT2_B   (OVL_B + 0ull)           // bf16 [4][1024][128]     1 MB
#define XTT2_B  (OVL_B + 1048576ull)     // bf16 [4][128][1024]     1 MB
#define XT4_B   (OVL_B + 2097152ull)     // bf16 [4][256][128]
#define XTT4_B  (OVL_B + 2359296ull)     // bf16 [4][128][256]
#define A2P_B   (OVL_B + 2621440ull)     // bf16 [8][4][128][1024]  8 MB
#define ML2_B   (OVL_B + 11010048ull)    // f32  [8][4][1024][2]    256 KB
#define A4P_B   (OVL_B + 11272192ull)    // bf16 [2][4][128][256]   512 KB
#define ML4_B   (OVL_B + 11796480ull)    // f32  [2][4][256][2]     16 KB
#define O1P_B   8388608ull         // bf16 [4][4][128][4096]       16 MB
#define ML1_B   25165824ull        // f32  [4][4][4096][2]         512 KB
#define A2M_B   25690112ull        // bf16 [4][128][1024]          1 MB
#define A4M_B   26738688ull        // bf16 [4][128][256]           256 KB

#define LOG2E 1.4426950408889634f

__device__ __forceinline__ float ex2(float x) { return __builtin_amdgcn_exp2f(x); }

__device__ __forceinline__ unsigned short f2bf(float f) {
    unsigned int u = __builtin_bit_cast(unsigned int, f);
    return (unsigned short)((u + 0x7FFFu + ((u >> 16) & 1u)) >> 16);
}
__device__ __forceinline__ float bf2f(unsigned short u) {
    unsigned int x = ((unsigned int)u) << 16;
    return __builtin_bit_cast(float, x);
}
__device__ __forceinline__ unsigned int pkbf(float lo, float hi) {
    union { __hip_bfloat162 h; unsigned int u; } c;
    c.h = __float22bfloat162_rn(make_float2(lo, hi));
    return c.u;
}
__device__ __forceinline__ void gload_lds16(const void* g, void* l) {
    __builtin_amdgcn_global_load_lds(
        (const __attribute__((address_space(1))) unsigned int*)g,
        (__attribute__((address_space(3))) unsigned int*)l, 16, 0, 0);
}

// ---------------- fused pool: x[B][C][64][64] -> {xt,xtT} for scales 1,2,4
__global__ __launch_bounds__(256) void pool_all(const float* __restrict__ x,
                                                unsigned short* __restrict__ xt1,
                                                unsigned short* __restrict__ xtT1,
                                                unsigned short* __restrict__ xt2,
                                                unsigned short* __restrict__ xtT2,
                                                unsigned short* __restrict__ xt4,
                                                unsigned short* __restrict__ xtT4) {
    constexpr int RS = 257;
    __shared__ float lds[32 * RS];
    const int hp4 = blockIdx.x;
    const int c0  = blockIdx.y * 32;
    const int b   = blockIdx.z;
    const int t   = threadIdx.x;

    #pragma unroll
    for (int i = 0; i < 8; ++i) {
        int e4 = (i * 256 + t) * 4;
        int ci = e4 >> 8, rem = e4 & 255;
        float4 v = *reinterpret_cast<const float4*>(
            &x[((size_t)(b * C_ + c0 + ci) * 64 + (hp4 * 4 + (rem >> 6))) * 64 + (rem & 63)]);
        *reinterpret_cast<float4*>(&lds[ci * RS + rem]) = v;
    }
    __syncthreads();

    #pragma unroll
    for (int i = 0; i < 32; ++i) {
        int v = i * 256 + t;
        int ci = v & 31, pos = v >> 5;
        xt1[((size_t)b * 4096 + hp4 * 256 + pos) * C_ + c0 + ci] = f2bf(lds[ci * RS + pos]);
    }
    #pragma unroll
    for (int i = 0; i < 32; ++i) {
        int ci = i, pos = t;
        xtT1[((size_t)(b * C_ + c0 + ci)) * 4096 + hp4 * 256 + pos] = f2bf(lds[ci * RS + pos]);
    }
    #pragma unroll
    for (int i = 0; i < 8; ++i) {
        int v = i * 256 + t;
        int ci = v & 31, pz = v >> 5;
        int r2 = pz >> 5, w2 = pz & 31;
        float s = lds[ci * RS + (2*r2)*64 + 2*w2]     + lds[ci * RS + (2*r2)*64 + 2*w2 + 1]
                + lds[ci * RS + (2*r2+1)*64 + 2*w2]   + lds[ci * RS + (2*r2+1)*64 + 2*w2 + 1];
        xt2[((size_t)b * 1024 + (hp4*2 + r2)*32 + w2) * C_ + c0 + ci] = f2bf(s * 0.25f);
    }
    #pragma unroll
    for (int i = 0; i < 8; ++i) {
        int v = i * 256 + t;
        int pz = v & 63, ci = v >> 6;
        int r2 = pz >> 5, w2 = pz & 31;
        float s = lds[ci * RS + (2*r2)*64 + 2*w2]     + lds[ci * RS + (2*r2)*64 + 2*w2 + 1]
                + lds[ci * RS + (2*r2+1)*64 + 2*w2]   + lds[ci * RS + (2*r2+1)*64 + 2*w2 + 1];
        xtT2[((size_t)(b * C_ + c0 + ci)) * 1024 + (hp4*2 + r2)*32 + w2] = f2bf(s * 0.25f);
    }
    #pragma unroll
    for (int i = 0; i < 2; ++i) {
        int v = i * 256 + t;
        int ci = v & 31, w4 = v >> 5;
        float s = 0.f;
        #pragma unroll
        for (int r = 0; r < 4; ++r)
            #pragma unroll
            for (int j = 0; j < 4; ++j) s += lds[ci * RS + r*64 + w4*4 + j];
        xt4[((size_t)b * 256 + hp4*16 + w4) * C_ + c0 + ci] = f2bf(s * 0.0625f);
    }
    #pragma unroll
    for (int i = 0; i < 2; ++i) {
        int v = i * 256 + t;
        int w4 = v & 15, ci = v >> 4;
        float s = 0.f;
        #pragma unroll
        for (int r = 0; r < 4; ++r)
            #pragma unroll
            for (int j = 0; j < 4; ++j) s += lds[ci * RS + r*64 + w4*4 + j];
        xtT4[((size_t)(b * C_ + c0 + ci)) * 256 + hp4*16 + w4] = f2bf(s * 0.0625f);
    }
}

// ---------------- MFMA flash attention, cross-tile software pipeline.
// Split K/V double buffers (4 x 16 KB). Per body: vmcnt(8); s_barrier;
// {QK^T(t+1) || softmax(t)}; PV(t); s_barrier; stage K(t+3), V(t+2).
// Counted vmcnt keeps 8 loads in flight across barriers (one body of cover).
template<int N, int SPLIT>
__device__ __forceinline__ void attn_body(const unsigned short* __restrict__ xt,
                                          const unsigned short* __restrict__ xtT,
                                          unsigned short* __restrict__ op,
                                          float* __restrict__ ml,
                                          const int bid, char* lds) {
    constexpr int LOG2S = (SPLIT == 2) ? 1 : ((SPLIT == 4) ? 2 : 3);
    constexpr int QB = N / 128;
    constexpr int W2 = QB * SPLIT / 2;
    constexpr int NT = N / SPLIT / 64;
    static_assert(NT >= 2 && (NT & 1) == 0, "even NT >= 2 required");
    const int xcd   = bid & 7;
    const int b     = xcd >> 1;                 // batch pinned to XCD pair (L2 locality)
    const int wi    = (xcd & 1) * W2 + (bid >> 3);
    const int split = wi & (SPLIT - 1);
    const int qx    = wi >> LOG2S;
    const int n0    = qx * 128;
    const int m_beg = split * (N / SPLIT);

    const int tid = threadIdx.x;
    const int w = tid >> 6, lane = tid & 63;
    const int g = lane >> 4, rho = lane & 15;

    const char* xb  = (const char*)(xt  + (size_t)b * N * C_);
    const char* xtb = (const char*)(xtT + (size_t)b * C_ * N);

    // Q fragments (B-operand of S^T mfma), pre-scaled by log2e
    bf16x8 qf[2][4];
    #pragma unroll
    for (int tt = 0; tt < 2; ++tt) {
        const char* qr = xb + (size_t)(n0 + w * 32 + tt * 16 + rho) * 256;
        #pragma unroll
        for (int kc = 0; kc < 4; ++kc) {
            bf16x8 raw = *(const bf16x8*)(qr + kc * 64 + g * 16);
            bf16x8 s;
            #pragma unroll
            for (int e = 0; e < 8; ++e)
                s[e] = (short)f2bf(bf2f((unsigned short)raw[e]) * LOG2E);
            qf[tt][kc] = s;
        }
    }

    // per-lane constant offsets
    int kOff[4], vOff[4];
    #pragma unroll
    for (int k = 0; k < 4; ++k) {
        int D = (w * 4 + k) * 1024 + lane * 16;
        int row = D >> 8, colb = D & 255;
        kOff[k] = row * 256 + (colb ^ ((row & 15) << 4));
        int c = D >> 7, cb2 = D & 127;
        vOff[k] = c * (2 * N) + (cb2 ^ ((c & 7) << 4));
    }
    int qkOff[4][4], pvOff[8][2];
    #pragma unroll
    for (int mb = 0; mb < 4; ++mb) {
        int rowm = ((mb >> 1) << 5) + ((mb & 1) << 2) + ((rho >> 2) << 3) + (rho & 3);
        int swz = (rowm & 15) << 4;
        #pragma unroll
        for (int kc = 0; kc < 4; ++kc)
            qkOff[mb][kc] = rowm * 256 + ((kc * 64 + g * 16) ^ swz);
    }
    #pragma unroll
    for (int cb = 0; cb < 8; ++cb) {
        int c = cb * 16 + rho;
        int vswz = (c & 7) << 4;
        #pragma unroll
        for (int ks = 0; ks < 2; ++ks)
            pvOff[cb][ks] = c * 128 + ((ks * 64 + g * 16) ^ vswz);
    }

    char* const KB0 = lds;
    char* const KB1 = lds + 16384;
    char* const VB0 = lds + 32768;
    char* const VB1 = lds + 49152;
    const char* kG = xb  + (size_t)m_beg * 256;
    const char* vG = xtb + (size_t)m_beg * 2;

    auto stageK = [&](char* dst, int tile) {
        const char* s = kG + (size_t)tile * (64 * 256);
        #pragma unroll
        for (int k = 0; k < 4; ++k) gload_lds16(s + kOff[k], dst + (w * 4 + k) * 1024);
    };
    auto stageV = [&](char* dst, int tile) {
        const char* s = vG + (size_t)tile * (64 * 2);
        #pragma unroll
        for (int k = 0; k < 4; ++k) gload_lds16(s + vOff[k], dst + (w * 4 + k) * 1024);
    };

    f32x4 acc[2][8];
    #pragma unroll
    for (int tt = 0; tt < 2; ++tt)
        #pragma unroll
        for (int cb = 0; cb < 8; ++cb) acc[tt][cb] = (f32x4){0.f, 0.f, 0.f, 0.f};
    float m_run[2] = {-INFINITY, -INFINITY};
    float l_lane[2] = {0.f, 0.f};

    auto qkt = [&](const char* kb, f32x4 (&aS)[2][4]) {
        #pragma unroll
        for (int tt = 0; tt < 2; ++tt)
            #pragma unroll
            for (int mb = 0; mb < 4; ++mb) aS[tt][mb] = (f32x4){0.f, 0.f, 0.f, 0.f};
        __builtin_amdgcn_s_setprio(1);
        #pragma unroll
        for (int mb = 0; mb < 4; ++mb)
            #pragma unroll
            for (int kc = 0; kc < 4; ++kc) {
                bf16x8 kf = *(const bf16x8*)(kb + qkOff[mb][kc]);
                aS[0][mb] = __builtin_amdgcn_mfma_f32_16x16x32_bf16(kf, qf[0][kc], aS[0][mb], 0, 0, 0);
                aS[1][mb] = __builtin_amdgcn_mfma_f32_16x16x32_bf16(kf, qf[1][kc], aS[1][mb], 0, 0, 0);
            }
        __builtin_amdgcn_s_setprio(0);
    };

    auto smpv = [&](f32x4 (&aS)[2][4], const char* vb) {
        bf16x8 pb[2][2];
        #pragma unroll
        for (int tt = 0; tt < 2; ++tt) {
            float tm = aS[tt][0][0];
            #pragma unroll
            for (int mb = 0; mb < 4; ++mb)
                #pragma unroll
                for (int r = 0; r < 4; ++r) tm = fmaxf(tm, aS[tt][mb][r]);
            tm = fmaxf(tm, __shfl_xor(tm, 16));
            tm = fmaxf(tm, __shfl_xor(tm, 32));
            if (!__all(tm <= m_run[tt] + 6.0f)) {
                float nm = fmaxf(m_run[tt], tm);
                float sc = ex2(m_run[tt] - nm);
                l_lane[tt] *= sc;
                m_run[tt] = nm;
                #pragma unroll
                for (int cb = 0; cb < 8; ++cb) {
                    acc[tt][cb][0] *= sc; acc[tt][cb][1] *= sc;
                    acc[tt][cb][2] *= sc; acc[tt][cb][3] *= sc;
                }
            }
            float p[4][4];
            #pragma unroll
            for (int mb = 0; mb < 4; ++mb)
                #pragma unroll
                for (int r = 0; r < 4; ++r) {
                    p[mb][r] = ex2(aS[tt][mb][r] - m_run[tt]);
                    l_lane[tt] += p[mb][r];
                }
            #pragma unroll
            for (int ks = 0; ks < 2; ++ks) {
                union { bf16x8 v; unsigned int u[4]; } pk;
                pk.u[0] = pkbf(p[2 * ks][0],     p[2 * ks][1]);
                pk.u[1] = pkbf(p[2 * ks][2],     p[2 * ks][3]);
                pk.u[2] = pkbf(p[2 * ks + 1][0], p[2 * ks + 1][1]);
                pk.u[3] = pkbf(p[2 * ks + 1][2], p[2 * ks + 1][3]);
                pb[tt][ks] = pk.v;
            }
        }
        __builtin_amdgcn_s_setprio(1);
        #pragma unroll
        for (int cb = 0; cb < 8; ++cb)
            #pragma unroll
            for (int ks = 0; ks < 2; ++ks) {
                bf16x8 vf = *(const bf16x8*)(vb + pvOff[cb][ks]);
                acc[0][cb] = __builtin_amdgcn_mfma_f32_16x16x32_bf16(vf, pb[0][ks], acc[0][cb], 0, 0, 0);
                acc[1][cb] = __builtin_amdgcn_mfma_f32_16x16x32_bf16(vf, pb[1][ks], acc[1][cb], 0, 0, 0);
            }
        __builtin_amdgcn_s_setprio(0);
    };

    f32x4 accA[2][4], accB[2][4];

    // prologue: K0,V0,K1,V1 staged; QK^T(0); then K2 reuses KB0
    stageK(KB0, 0); stageV(VB0, 0); stageK(KB1, 1); stageV(VB1, 1);
    asm volatile("s_waitcnt vmcnt(12)" ::: "memory");   // K0 complete
    __builtin_amdgcn_s_barrier();
    qkt(KB0, accA);
    __builtin_amdgcn_s_barrier();                        // all waves done with KB0
    if constexpr (NT > 2) stageK(KB0, 2);

    #pragma unroll 1
    for (int j = 0; j + 3 < NT; j += 2) {
        // body even (tile j): QK^T(j+1) || softmax(j); PV(j)
        asm volatile("s_waitcnt vmcnt(8)" ::: "memory");
        __builtin_amdgcn_s_barrier();
        qkt(KB1, accB);
        smpv(accA, VB0);
        __builtin_amdgcn_s_barrier();
        stageK(KB1, j + 3);
        stageV(VB0, j + 2);
        // body odd (tile j+1)
        asm volatile("s_waitcnt vmcnt(8)" ::: "memory");
        __builtin_amdgcn_s_barrier();
        qkt(KB0, accA);
        smpv(accB, VB1);
        __builtin_amdgcn_s_barrier();
        if (j + 4 < NT) stageK(KB0, j + 4);
        stageV(VB1, j + 3);
    }
    // final body (tile NT-2): QK^T(NT-1) || softmax(NT-2); PV(NT-2)
    asm volatile("s_waitcnt vmcnt(4)" ::: "memory");
    __builtin_amdgcn_s_barrier();
    qkt(KB1, accB);
    smpv(accA, VB0);
    // last tile NT-1
    asm volatile("s_waitcnt vmcnt(0)" ::: "memory");
    __builtin_amdgcn_s_barrier();
    smpv(accB, VB1);

    // epilogue: reduce l across g-lanes, store unnormalized partials + (m,l)
    #pragma unroll
    for (int tt = 0; tt < 2; ++tt) {
        l_lane[tt] += __shfl_xor(l_lane[tt], 16);
        l_lane[tt] += __shfl_xor(l_lane[tt], 32);
        const int n = n0 + w * 32 + tt * 16 + rho;
        #pragma unroll
        for (int cb = 0; cb < 8; ++cb)
            #pragma unroll
            for (int r = 0; r < 4; ++r)
                op[((size_t)(split * B_ + b) * C_ + cb * 16 + g * 4 + r) * N + n] = f2bf(acc[tt][cb][r]);
        if (g == 0) {
            ml[((size_t)(split * B_ + b) * N + n) * 2 + 0] = m_run[tt];
            ml[((size_t)(split * B_ + b) * N + n) * 2 + 1] = l_lane[tt];
        }
    }
}

__global__ __launch_bounds__(256, 2) void attn_mfma(const unsigned short* __restrict__ xt,
                                                    const unsigned short* __restrict__ xtT,
                                                    unsigned short* __restrict__ op,
                                                    float* __restrict__ ml) {
    __shared__ char lds[65536];
    attn_body<4096, 4>(xt, xtT, op, ml, (int)blockIdx.x, lds);
}

// scale-2 (blocks 0..255) and scale-4 (blocks 256..271) in one launch
__global__ __launch_bounds__(256, 2) void attn_small(const unsigned short* __restrict__ xt2,
                                                     const unsigned short* __restrict__ xtT2,
                                                     unsigned short* __restrict__ a2p,
                                                     float* __restrict__ ml2,
                                                     const unsigned short* __restrict__ xt4,
                                                     const unsigned short* __restrict__ xtT4,
                                                     unsigned short* __restrict__ a4p,
                                                     float* __restrict__ ml4) {
    __shared__ char lds[65536];
    if (blockIdx.x < 256)
        attn_body<1024, 8>(xt2, xtT2, a2p, ml2, (int)blockIdx.x, lds);
    else
        attn_body<256, 2>(xt4, xtT4, a4p, ml4, (int)blockIdx.x - 256, lds);
}

// ---------------- merge partials: scale-2 (8-way) and scale-4 (2-way)
__global__ __launch_bounds__(256) void merge_small(const unsigned short* __restrict__ a2p,
                                                   const float* __restrict__ ml2,
                                                   const unsigned short* __restrict__ a4p,
                                                   const float* __restrict__ ml4,
                                                   unsigned short* __restrict__ a2m,
                                                   unsigned short* __restrict__ a4m) {
    int idx = blockIdx.x * 256 + threadIdx.x;
    if (idx < 4 * 128 * 1024) {
        int n = idx & 1023, c = (idx >> 10) & 127, b = idx >> 17;
        float M = -INFINITY;
        #pragma unroll
        for (int s = 0; s < 8; ++s) M = fmaxf(M, ml2[((s * 4 + b) * 1024 + n) * 2]);
        float L = 0.f, O = 0.f;
        #pragma unroll
        for (int s = 0; s < 8; ++s) {
            float wgt = ex2(ml2[((s * 4 + b) * 1024 + n) * 2] - M);
            L += ml2[((s * 4 + b) * 1024 + n) * 2 + 1] * wgt;
            O += bf2f(a2p[((size_t)((s * 4 + b) * 128 + c)) * 1024 + n]) * wgt;
        }
        a2m[((size_t)(b * 128 + c)) * 1024 + n] = f2bf(O / L);
    } else {
        int i2 = idx - 4 * 128 * 1024;
        if (i2 < 4 * 128 * 256) {
            int n = i2 & 255, c = (i2 >> 8) & 127, b = i2 >> 15;
            float M = fmaxf(ml4[((0 * 4 + b) * 256 + n) * 2], ml4[((1 * 4 + b) * 256 + n) * 2]);
            float L = 0.f, O = 0.f;
            #pragma unroll
            for (int s = 0; s < 2; ++s) {
                float wgt = ex2(ml4[((s * 4 + b) * 256 + n) * 2] - M);
                L += ml4[((s * 4 + b) * 256 + n) * 2 + 1] * wgt;
                O += bf2f(a4p[((size_t)((s * 4 + b) * 128 + c)) * 256 + n]) * wgt;
            }
            a4m[((size_t)(b * 128 + c)) * 256 + n] = f2bf(O / L);
        }
    }
}

// ---------------- bilinear upsample (half-pixel centers, clamp) from bf16 grid
template<int HS>
__device__ __forceinline__ float bilin(const unsigned short* __restrict__ a, int h, int w) {
    constexpr float sc = (float)HS / 64.0f;
    float sh = (h + 0.5f) * sc - 0.5f;
    float sw = (w + 0.5f) * sc - 0.5f;
    int h0 = (int)floorf(sh); float fh = sh - (float)h0;
    int w0 = (int)floorf(sw); float fw = sw - (float)w0;
    int h0c = max(h0, 0), h1c = min(h0 + 1, HS - 1);
    int w0c = max(w0, 0), w1c = min(w0 + 1, HS - 1);
    float v00 = bf2f(a[h0c * HS + w0c]), v01 = bf2f(a[h0c * HS + w1c]);
    float v10 = bf2f(a[h1c * HS + w0c]), v11 = bf2f(a[h1c * HS + w1c]);
    return (1.f - fh) * ((1.f - fw) * v00 + fw * v01)
         +        fh  * ((1.f - fw) * v10 + fw * v11);
}

__global__ __launch_bounds__(256) void combine_kernel(float* __restrict__ out,
                                                      const unsigned short* __restrict__ o1p,
                                                      const float* __restrict__ ml1,
                                                      const unsigned short* __restrict__ a2m,
                                                      const unsigned short* __restrict__ a4m) {
    int e = blockIdx.x * 256 + threadIdx.x;
    if (e >= B_ * C_ * 64 * 64) return;
    int w  = e & 63;
    int h  = (e >> 6) & 63;
    int bc = e >> 12;
    int b  = bc >> 7;
    int n  = (h << 6) | w;
    float M = -INFINITY;
    #pragma unroll
    for (int s = 0; s < 4; ++s) M = fmaxf(M, ml1[((size_t)(s * 4 + b) * 4096 + n) * 2]);
    float num = 0.f, den = 0.f;
    #pragma unroll
    for (int s = 0; s < 4; ++s) {
        float wgt = ex2(ml1[((size_t)(s * 4 + b) * 4096 + n) * 2] - M);
        den += ml1[((size_t)(s * 4 + b) * 4096 + n) * 2 + 1] * wgt;
        num += bf2f(o1p[((size_t)(s * 512 + bc)) * 4096 + n]) * wgt;
    }
    float v = num / den;
    v += bilin<32>(a2m + (size_t)bc * 1024, h, w);
    v += bilin<16>(a4m + (size_t)bc * 256,  h, w);
    out[e] = v;
}

extern "C" void kernel_launch(void* const* d_in, const int* in_sizes, int n_in,
                              void* d_out, int out_size, void* d_ws, size_t ws_size,
                              hipStream_t stream) {
    const float* x = (const float*)d_in[0];
    float* out = (float*)d_out;
    char* ws = (char*)d_ws;
    unsigned short* xt1  = (unsigned short*)(ws + XT1_B);
    unsigned short* xtT1 = (unsigned short*)(ws + XTT1_B);
    unsigned short* xt2  = (unsigned short*)(ws + XT2_B);
    unsigned short* xtT2 = (unsigned short*)(ws + XTT2_B);
    unsigned short* xt4  = (unsigned short*)(ws + XT4_B);
    unsigned short* xtT4 = (unsigned short*)(ws + XTT4_B);
    unsigned short* a2p  = (unsigned short*)(ws + A2P_B);
    float*          ml2  = (float*)(ws + ML2_B);
    unsigned short* a4p  = (unsigned short*)(ws + A4P_B);
    float*          ml4  = (float*)(ws + ML4_B);
    unsigned short* o1p  = (unsigned short*)(ws + O1P_B);
    float*          ml1  = (float*)(ws + ML1_B);
    unsigned short* a2m  = (unsigned short*)(ws + A2M_B);
    unsigned short* a4m  = (unsigned short*)(ws + A4M_B);

    // Phase A: fused pool + small scales (one launch) + their merge
    pool_all<<<dim3(16, 4, B_), 256, 0, stream>>>(x, xt1, xtT1, xt2, xtT2, xt4, xtT4);
    attn_small<<<272, 256, 0, stream>>>(xt2, xtT2, a2p, ml2, xt4, xtT4, a4p, ml4);
    merge_small<<<2560, 256, 0, stream>>>(a2p, ml2, a4p, ml4, a2m, a4m);

    // Phase B: scale-1 (o1p overwrites the overlap region) + final combine
    attn_mfma<<<512, 256, 0, stream>>>(xt1, xtT1, o1p, ml1);
    combine_kernel<<<(B_ * C_ * 64 * 64 + 255) / 256, 256, 0, stream>>>(out, o1p, ml1, a2m, a4m);
}